// Round 10
// baseline (211.211 us; speedup 1.0000x reference)
//
#include <hip/hip_runtime.h>

// MHA: BS=4 SEQ=2048 D_MODEL=1024 H=16 DH=64
// R10 = R9 + gemm_bt converted to prefetch-next double-buffered K-loop
// (T3-minimum 2-phase): issue staging for tile kt+1 into LDS buf^1 (gll16)
// or regs (f32 path) BEFORE computing tile kt; reg path ds_writes after
// compute (T14); ONE __syncthreads per K-step (its vmcnt drain now lands
// after a full compute phase). Attn unchanged from R9.

typedef __attribute__((ext_vector_type(8))) unsigned short us8;
typedef __attribute__((ext_vector_type(4))) unsigned short us4;
typedef __attribute__((ext_vector_type(4))) int i4;
typedef __attribute__((ext_vector_type(4))) float f4;
typedef __attribute__((ext_vector_type(4))) float f32x4;
typedef __attribute__((ext_vector_type(8))) __bf16 bf16x8;
typedef __attribute__((ext_vector_type(2))) unsigned u32x2;
typedef __attribute__((ext_vector_type(4))) unsigned u32x4;

#define DEV static __device__ __forceinline__

DEV unsigned short f2bf(float f){
  unsigned u = __builtin_bit_cast(unsigned, f);
  u = (u + 0x7fffu + ((u >> 16) & 1u)) >> 16;
  return (unsigned short)u;
}

DEV bf16x8 ld_frag(const unsigned short* p){
  return __builtin_bit_cast(bf16x8, *(const us8*)p);
}

// async global->LDS, 16B per lane. LDS dest wave-uniform base + lane*16; global src per-lane.
DEV void gll16(const unsigned short* gsrc, unsigned short* ldst){
  __builtin_amdgcn_global_load_lds(
      (const __attribute__((address_space(1))) unsigned int*)gsrc,
      (__attribute__((address_space(3))) unsigned int*)ldst, 16, 0, 0);
}

// load 8 f32, convert to 8 bf16 via packed cvt (RNE)
DEV us8 ld_cvt_f32x8(const float* p){
  f4 v0 = *(const f4*)p;
  f4 v1 = *(const f4*)(p + 4);
  unsigned d0, d1, d2, d3;
  asm("v_cvt_pk_bf16_f32 %0, %1, %2" : "=v"(d0) : "v"(v0[0]), "v"(v0[1]));
  asm("v_cvt_pk_bf16_f32 %0, %1, %2" : "=v"(d1) : "v"(v0[2]), "v"(v0[3]));
  asm("v_cvt_pk_bf16_f32 %0, %1, %2" : "=v"(d2) : "v"(v1[0]), "v"(v1[1]));
  asm("v_cvt_pk_bf16_f32 %0, %1, %2" : "=v"(d3) : "v"(v1[2]), "v"(v1[3]));
  u32x4 u = {d0, d1, d2, d3};
  return __builtin_bit_cast(us8, u);
}

// ---------------- f32 -> bf16 conversion (weights only) ----------------
__global__ void cvt_bf16(const float* __restrict__ in, unsigned short* __restrict__ out, int n8){
  int i = blockIdx.x * 256 + threadIdx.x;
  if(i >= n8) return;
  *(us8*)(out + (size_t)i * 8) = ld_cvt_f32x8(in + (size_t)i * 8);
}

// ---------------- mask scan: compacted unmasked-key index list ----------------
__global__ __launch_bounds__(256) void mask_scan(
    const int* __restrict__ mask, int* __restrict__ idx, int* __restrict__ nk)
{
  const int b = blockIdx.x, t = threadIdx.x;
  __shared__ int sc[256];
  int m[8]; int c = 0;
#pragma unroll
  for(int r = 0; r < 8; ++r){ m[r] = mask[b * 2048 + t * 8 + r]; c += (m[r] != 0); }
  sc[t] = c;
  __syncthreads();
  for(int s = 1; s < 256; s <<= 1){
    int v = (t >= s) ? sc[t - s] : 0;
    __syncthreads();
    sc[t] += v;
    __syncthreads();
  }
  int pos = sc[t] - c;            // exclusive prefix
  int total = sc[255];
#pragma unroll
  for(int r = 0; r < 8; ++r) if(m[r]) idx[b * 2048 + pos++] = t * 8 + r;
  int pend = (total + 127) & ~127;
  for(int p = total + t; p < pend; p += 256) idx[b * 2048 + p] = 0;
  if(t == 0) nk[b] = total;
}

// ---------------- GEMM: C = A @ B^T (+bias), A[M][K], B[N][K] ----------------
// Double-buffered prefetch-next K-loop. GATHER: 0 none, 1 = A f32 rows via idx,
// 2 = B f32 rows via idx (per-batch compacted; fully-past blocks exit).
template<int MODE, bool AF32, bool BF32, int GATHER>
__global__ __launch_bounds__(256) void gemm_bt(
    const void* __restrict__ Ap, const void* __restrict__ Bp,
    const float* __restrict__ bias, void* __restrict__ outp,
    int M, int N, int K, float scale,
    const int* __restrict__ gidx, const int* __restrict__ nkarr)
{
  __shared__ __align__(16) unsigned short As[2][128 * 64];
  __shared__ __align__(16) unsigned short Bs[2][128 * 64];
  const int tid = threadIdx.x;
  const int gx = blockIdx.x, gy = blockIdx.y;      // gx: N-tile, gy: M-tile
  const int w = tid >> 6, l = tid & 63, g = l >> 4, l15 = l & 15;
  const int wm = w >> 1, wn = w & 1;
  const int xsw = ((l & 7) ^ (l >> 3)) << 3;
  const int ch = tid & 7, srow = tid >> 3;

  int ia[4];                                        // gathered row indices
  int gb = 0;
  if constexpr(GATHER != 0){
    const int tilerow = (GATHER == 1) ? gy : gx;
    gb = (tilerow * 128) >> 11;
    const int j0 = (tilerow * 128) & 2047;
    const int total = nkarr[gb];
    if(j0 >= ((total + 127) & ~127)) return;        // uniform exit, pre-barrier
#pragma unroll
    for(int i = 0; i < 4; ++i)
      ia[i] = gidx[gb * 2048 + j0 + srow + i * 32];
  }

  f32x4 acc[4][4];
#pragma unroll
  for(int a = 0; a < 4; ++a)
#pragma unroll
    for(int b = 0; b < 4; ++b) acc[a][b] = (f32x4){0.f,0.f,0.f,0.f};

  us8 arp[4], brp[4];                               // pending reg-staged data

  auto stageA = [&](int kt, int nb){
    if constexpr(AF32){
#pragma unroll
      for(int i = 0; i < 4; ++i){
        const float* src;
        if constexpr(GATHER == 1)
          src = (const float*)Ap + ((size_t)gb * 2048 + ia[i]) * K + kt * 64 + ch * 8;
        else
          src = (const float*)Ap + (size_t)(gy * 128 + srow + i * 32) * K + kt * 64 + ch * 8;
        arp[i] = ld_cvt_f32x8(src);
      }
    } else {
      const unsigned short* Ab = (const unsigned short*)Ap;
#pragma unroll
      for(int j = 0; j < 4; ++j)
        gll16(Ab + (size_t)(gy * 128 + (w << 5) + (j << 3) + (l >> 3)) * K + kt * 64 + xsw,
              &As[nb][((w << 5) + (j << 3)) << 6]);
    }
  };
  auto stageB = [&](int kt, int nb){
    if constexpr(BF32){
#pragma unroll
      for(int i = 0; i < 4; ++i){
        const float* src;
        if constexpr(GATHER == 2)
          src = (const float*)Bp + ((size_t)gb * 2048 + ia[i]) * K + kt * 64 + ch * 8;
        else
          src = (const float*)Bp + (size_t)(gx * 128 + srow + i * 32) * K + kt * 64 + ch * 8;
        brp[i] = ld_cvt_f32x8(src);
      }
    } else {
      const unsigned short* Bb = (const unsigned short*)Bp;
#pragma unroll
      for(int j = 0; j < 4; ++j)
        gll16(Bb + (size_t)(gx * 128 + (w << 5) + (j << 3) + (l >> 3)) * K + kt * 64 + xsw,
              &Bs[nb][((w << 5) + (j << 3)) << 6]);
    }
  };
  auto writeA = [&](int nb){
    if constexpr(AF32){
#pragma unroll
      for(int i = 0; i < 4; ++i){
        int row = srow + i * 32;
        *(us8*)&As[nb][row * 64 + ((ch * 8) ^ ((row & 7) << 3))] = arp[i];
      }
    }
  };
  auto writeB = [&](int nb){
    if constexpr(BF32){
#pragma unroll
      for(int i = 0; i < 4; ++i){
        int row = srow + i * 32;
        *(us8*)&Bs[nb][row * 64 + ((ch * 8) ^ ((row & 7) << 3))] = brp[i];
      }
    }
  };

  const int nkt = K >> 6;
  // prologue: tile 0 into buffer 0
  stageA(0, 0); stageB(0, 0);
  writeA(0);    writeB(0);
  __syncthreads();                                  // drains vmcnt for gll16 path

  for(int kt = 0; kt < nkt; ++kt){
    const int cur = kt & 1, nxt = cur ^ 1;
    if(kt + 1 < nkt){ stageA(kt + 1, nxt); stageB(kt + 1, nxt); }  // prefetch

#pragma unroll
    for(int kk = 0; kk < 2; ++kk){
      bf16x8 af[4], bg[4];
#pragma unroll
      for(int mi = 0; mi < 4; ++mi){
        int row = wm * 64 + mi * 16 + l15;
        af[mi] = ld_frag(&As[cur][row * 64 + ((kk * 32 + g * 8) ^ ((row & 7) << 3))]);
      }
#pragma unroll
      for(int ni = 0; ni < 4; ++ni){
        int row = wn * 64 + ni * 16 + l15;
        bg[ni] = ld_frag(&Bs[cur][row * 64 + ((kk * 32 + g * 8) ^ ((row & 7) << 3))]);
      }
#pragma unroll
      for(int mi = 0; mi < 4; ++mi)
#pragma unroll
        for(int ni = 0; ni < 4; ++ni)
          acc[mi][ni] = __builtin_amdgcn_mfma_f32_16x16x32_bf16(af[mi], bg[ni], acc[mi][ni], 0, 0, 0);
    }

    if(kt + 1 < nkt){ writeA(nxt); writeB(nxt); }   // T14: write after compute
    __syncthreads();                                // single barrier per K-step
  }

  // epilogue
#pragma unroll
  for(int mi = 0; mi < 4; ++mi)
#pragma unroll
    for(int ni = 0; ni < 4; ++ni){
      int gmb = gy * 128 + wm * 64 + mi * 16 + g * 4;
      int gn  = gx * 128 + wn * 64 + ni * 16 + l15;
#pragma unroll
      for(int r = 0; r < 4; ++r){
        int gm = gmb + r;
        float v = acc[mi][ni][r];
        if(MODE == 0){
          v = (v + bias[gn]) * scale;
          int b = gm >> 11, s = gm & 2047, h = gn >> 6, dh = gn & 63;
          ((unsigned short*)outp)[(size_t)(((b << 4) + h) * 2048 + s) * 64 + dh] = f2bf(v);
        } else if(MODE == 1){
          v = v + bias[gm];
          int h = gm >> 6, dh = gm & 63, b = gn >> 11, s = gn & 2047;
          ((unsigned short*)outp)[(size_t)(((b << 4) + h) * 64 + dh) * 2048 + s] = f2bf(v);
        } else {
          v = v + bias[gn];
          ((float*)outp)[(size_t)gm * N + gn] = v;
        }
      }
    }
}

// ---------------- Flash attention over compacted keys (unchanged from R9) ----------------
__global__ __launch_bounds__(256) void attn_kernel(
    const unsigned short* __restrict__ q, const unsigned short* __restrict__ ksc,
    const unsigned short* __restrict__ vTc, const int* __restrict__ nk,
    unsigned short* __restrict__ ctx)
{
  __shared__ __align__(16) unsigned short KsB[2][64 * 64];
  __shared__ __align__(16) unsigned short VtB[2][64 * 64];
  __shared__ __align__(16) unsigned short Ps[4][16 * 64];

  const int qt = blockIdx.x;
  const int bh = blockIdx.y;
  const int b  = bh >> 4, h = bh & 15;
  const int tid = threadIdx.x;
  const int w = tid >> 6, l = tid & 63, g = l >> 4, l15 = l & 15;
  const int rl = l >> 3, c8 = l & 7;

  const int nkb = nk[b];
  const int nt = (nkb + 63) >> 6;

  const unsigned short* qbase = q + ((size_t)(bh * 2048 + qt * 64 + w * 16 + l15)) * 64;
  bf16x8 bq[2];
  bq[0] = ld_frag(qbase + g * 8);
  bq[1] = ld_frag(qbase + 32 + g * 8);

  const unsigned short* kbase = ksc + (size_t)bh * 2048 * 64;
  const unsigned short* vbase = vTc + (size_t)bh * 64 * 2048;

  const unsigned short* kg0 = kbase + (size_t)(w * 16 + rl) * 64 + c8 * 8;
  const unsigned short* vg0 = vbase + (size_t)(w * 16 + rl) * 2048 + c8 * 8;
  const int lo0 = (w * 16 + rl) * 64 + ((c8 ^ rl) << 3);
  const int lo1 = lo0 + 8 * 64;

  us8 kr0, kr1, vr0, vr1;
#define LOAD_T(kt_) do{                                        \
    kr0 = *(const us8*)(kg0 + (size_t)(kt_) * 4096);           \
    kr1 = *(const us8*)(kg0 + (size_t)(kt_) * 4096 + 512);     \
    vr0 = *(const us8*)(vg0 + (size_t)(kt_) * 64);             \
    vr1 = *(const us8*)(vg0 + (size_t)(kt_) * 64 + 8 * 2048);  \
  }while(0)
#define WRITE_T(bb_) do{                                       \
    *(us8*)&KsB[bb_][lo0] = kr0;                               \
    *(us8*)&KsB[bb_][lo1] = kr1;                               \
    *(us8*)&VtB[bb_][lo0] = vr0;                               \
    *(us8*)&VtB[bb_][lo1] = vr1;                               \
  }while(0)

  f32x4 acc[4];
#pragma unroll
  for(int mi = 0; mi < 4; ++mi) acc[mi] = (f32x4){0.f,0.f,0.f,0.f};
  float ll = 0.f;

  LOAD_T(0);
  WRITE_T(0);
  __syncthreads();

  for(int kt = 0; kt < nt; ++kt){
    const int bb = kt & 1;
    if(kt + 1 < nt) LOAD_T(kt + 1);

    f32x4 sa[4];
#pragma unroll
    for(int mi = 0; mi < 4; ++mi) sa[mi] = (f32x4){0.f,0.f,0.f,0.f};
#pragma unroll
    for(int kk = 0; kk < 2; ++kk){
#pragma unroll
      for(int mi = 0; mi < 4; ++mi){
        int row = mi * 16 + l15;
        bf16x8 af = ld_frag(&KsB[bb][row * 64 + ((kk * 32 + g * 8) ^ ((row & 7) << 3))]);
        sa[mi] = __builtin_amdgcn_mfma_f32_16x16x32_bf16(af, bq[kk], sa[mi], 0, 0, 0);
      }
    }

    float p[4][4];
    if((kt + 1) * 64 <= nkb){
#pragma unroll
      for(int mi = 0; mi < 4; ++mi)
#pragma unroll
        for(int r = 0; r < 4; ++r){
          p[mi][r] = __builtin_amdgcn_exp2f(sa[mi][r]);
          ll += p[mi][r];
        }
    } else {
      int kb0 = kt * 64 + g * 4;
#pragma unroll
      for(int mi = 0; mi < 4; ++mi)
#pragma unroll
        for(int r = 0; r < 4; ++r){
          float e = __builtin_amdgcn_exp2f(sa[mi][r]);
          p[mi][r] = (kb0 + mi * 16 + r < nkb) ? e : 0.f;
          ll += p[mi][r];
        }
    }

#pragma unroll
    for(int mi = 0; mi < 4; ++mi){
      unsigned d0, d1;
      asm("v_cvt_pk_bf16_f32 %0, %1, %2" : "=v"(d0) : "v"(p[mi][0]), "v"(p[mi][1]));
      asm("v_cvt_pk_bf16_f32 %0, %1, %2" : "=v"(d1) : "v"(p[mi][2]), "v"(p[mi][3]));
      u32x2 dd = {d0, d1};
      *(u32x2*)&Ps[w][l15 * 64 + ((mi * 16 + g * 4) ^ ((l15 & 7) << 3))] = dd;
    }

#pragma unroll
    for(int kk = 0; kk < 2; ++kk){
      bf16x8 pb = ld_frag(&Ps[w][l15 * 64 + ((kk * 32 + g * 8) ^ ((l15 & 7) << 3))]);
#pragma unroll
      for(int mi = 0; mi < 4; ++mi){
        int row = mi * 16 + l15;
        bf16x8 av = ld_frag(&VtB[bb][row * 64 + ((kk * 32 + g * 8) ^ ((row & 7) << 3))]);
        acc[mi] = __builtin_amdgcn_mfma_f32_16x16x32_bf16(av, pb, acc[mi], 0, 0, 0);
      }
    }

    if(kt + 1 < nt) WRITE_T(bb ^ 1);
    __syncthreads();
  }

  ll += __shfl_xor(ll, 16);
  ll += __shfl_xor(ll, 32);
  float inv = 1.0f / ll;

  {
    int qrow = w * 16 + l15;
#pragma unroll
    for(int mi = 0; mi < 4; ++mi){
      us4 o;
#pragma unroll
      for(int r = 0; r < 4; ++r) o[r] = f2bf(acc[mi][r] * inv);
      *(us4*)&KsB[0][qrow * 64 + ((mi * 16 + g * 4) ^ ((qrow & 7) << 3))] = o;
    }
  }
  __syncthreads();
  {
    int qrow = tid >> 2, part = tid & 3;
    us8 v0 = *(const us8*)&KsB[0][qrow * 64 + ((part * 16)     ^ ((qrow & 7) << 3))];
    us8 v1 = *(const us8*)&KsB[0][qrow * 64 + ((part * 16 + 8) ^ ((qrow & 7) << 3))];
    size_t orow = ((size_t)b * 2048 + qt * 64 + qrow) * 1024 + h * 64 + part * 16;
    *(us8*)&ctx[orow] = v0;
    *(us8*)&ctx[orow + 8] = v1;
  }
#undef LOAD_T
#undef WRITE_T
}

// ---------------- launch ----------------
extern "C" void kernel_launch(void* const* d_in, const int* in_sizes, int n_in,
                              void* d_out, int out_size, void* d_ws, size_t ws_size,
                              hipStream_t stream) {
  const float* Qf = (const float*)d_in[0];
  const float* Kf = (const float*)d_in[1];
  const float* Vf = (const float*)d_in[2];
  const int*   Mk = (const int*)d_in[3];
  const float* Wq = (const float*)d_in[4];
  const float* bq = (const float*)d_in[5];
  const float* Wk = (const float*)d_in[6];
  const float* bk = (const float*)d_in[7];
  const float* Wv = (const float*)d_in[8];
  const float* bv = (const float*)d_in[9];
  const float* Wo = (const float*)d_in[10];
  const float* bo = (const float*)d_in[11];

  const size_t MB = 1u << 20;
  char* ws = (char*)d_ws;
  unsigned short* Wqb = (unsigned short*)(ws + 0 * MB);
  unsigned short* Wkb = (unsigned short*)(ws + 2 * MB);
  unsigned short* Wvb = (unsigned short*)(ws + 4 * MB);
  unsigned short* Wob = (unsigned short*)(ws + 6 * MB);
  unsigned short* qs  = (unsigned short*)(ws + 8 * MB);
  unsigned short* ksc = (unsigned short*)(ws + 24 * MB);
  unsigned short* vTc = (unsigned short*)(ws + 40 * MB);
  unsigned short* ctx = (unsigned short*)(ws + 56 * MB);
  int* idx = (int*)(ws + 72 * MB);
  int* nk  = (int*)(ws + 73 * MB);

  const int NW = 1024 * 1024;

  auto cvt = [&](const float* src, unsigned short* dst, int n){
    int n8 = n / 8;
    cvt_bf16<<<(n8 + 255) / 256, 256, 0, stream>>>(src, dst, n8);
  };
  cvt(Wq, Wqb, NW);
  cvt(Wk, Wkb, NW);
  cvt(Wv, Wvb, NW);
  cvt(Wo, Wob, NW);

  mask_scan<<<4, 256, 0, stream>>>(Mk, idx, nk);

  const float QSCALE = 0.125f * 1.4426950408889634f;  // 1/sqrt(d_head) * log2(e)
  dim3 blk(256);
  // Q-proj (full)
  gemm_bt<0, true, false, 0><<<dim3(8, 64), blk, 0, stream>>>(
      Qf, Wqb, bq, qs, 8192, 1024, 1024, QSCALE, nullptr, nullptr);
  // K-proj over compacted keys (A rows gathered)
  gemm_bt<0, true, false, 1><<<dim3(8, 64), blk, 0, stream>>>(
      Kf, Wkb, bk, ksc, 8192, 1024, 1024, 1.0f, idx, nk);
  // V-proj transposed over compacted keys (B rows gathered)
  gemm_bt<1, false, true, 2><<<dim3(64, 8), blk, 0, stream>>>(
      Wvb, Vf, bv, vTc, 1024, 8192, 1024, 1.0f, idx, nk);
  // attention over compacted keys
  attn_kernel<<<dim3(32, 64), blk, 0, stream>>>(qs, ksc, vTc, nk, ctx);
  // output projection -> f32
  gemm_bt<2, false, false, 0><<<dim3(8, 64), blk, 0, stream>>>(
      ctx, Wob, bo, d_out, 8192, 1024, 1024, 1.0f, nullptr, nullptr);
}

// Round 11
// 187.636 us; speedup vs baseline: 1.1256x; 1.1256x over previous
//
#include <hip/hip_runtime.h>

// MHA: BS=4 SEQ=2048 D_MODEL=1024 H=16 DH=64
// R11 = R9 (single-buffer gemm restored; R10 dbuf was -4us) + XCD-colocating
// grid map (SWAPG): for GEMMs whose BIG operand is the A/M-panel (Q/K/out
// proj), launch grid (Mtiles, Ntiles) with M = blockIdx.x so the 8 blocks
// sharing an A-panel get linear IDs = gy, 64+gy, ... == gy (mod 8) -> SAME
// XCD L2 (panel fetched once, reused 8x). V-proj already well-placed.
// Attn unchanged (R9, compacted keys).

typedef __attribute__((ext_vector_type(8))) unsigned short us8;
typedef __attribute__((ext_vector_type(4))) unsigned short us4;
typedef __attribute__((ext_vector_type(4))) int i4;
typedef __attribute__((ext_vector_type(4))) float f4;
typedef __attribute__((ext_vector_type(4))) float f32x4;
typedef __attribute__((ext_vector_type(8))) __bf16 bf16x8;
typedef __attribute__((ext_vector_type(2))) unsigned u32x2;
typedef __attribute__((ext_vector_type(4))) unsigned u32x4;

#define DEV static __device__ __forceinline__

DEV unsigned short f2bf(float f){
  unsigned u = __builtin_bit_cast(unsigned, f);
  u = (u + 0x7fffu + ((u >> 16) & 1u)) >> 16;
  return (unsigned short)u;
}

DEV bf16x8 ld_frag(const unsigned short* p){
  return __builtin_bit_cast(bf16x8, *(const us8*)p);
}

// async global->LDS, 16B per lane. LDS dest wave-uniform base + lane*16; global src per-lane.
DEV void gll16(const unsigned short* gsrc, unsigned short* ldst){
  __builtin_amdgcn_global_load_lds(
      (const __attribute__((address_space(1))) unsigned int*)gsrc,
      (__attribute__((address_space(3))) unsigned int*)ldst, 16, 0, 0);
}

// load 8 f32, convert to 8 bf16 via packed cvt (RNE)
DEV us8 ld_cvt_f32x8(const float* p){
  f4 v0 = *(const f4*)p;
  f4 v1 = *(const f4*)(p + 4);
  unsigned d0, d1, d2, d3;
  asm("v_cvt_pk_bf16_f32 %0, %1, %2" : "=v"(d0) : "v"(v0[0]), "v"(v0[1]));
  asm("v_cvt_pk_bf16_f32 %0, %1, %2" : "=v"(d1) : "v"(v0[2]), "v"(v0[3]));
  asm("v_cvt_pk_bf16_f32 %0, %1, %2" : "=v"(d2) : "v"(v1[0]), "v"(v1[1]));
  asm("v_cvt_pk_bf16_f32 %0, %1, %2" : "=v"(d3) : "v"(v1[2]), "v"(v1[3]));
  u32x4 u = {d0, d1, d2, d3};
  return __builtin_bit_cast(us8, u);
}

// ---------------- f32 -> bf16 conversion (weights only) ----------------
__global__ void cvt_bf16(const float* __restrict__ in, unsigned short* __restrict__ out, int n8){
  int i = blockIdx.x * 256 + threadIdx.x;
  if(i >= n8) return;
  *(us8*)(out + (size_t)i * 8) = ld_cvt_f32x8(in + (size_t)i * 8);
}

// ---------------- mask scan: compacted unmasked-key index list ----------------
__global__ __launch_bounds__(256) void mask_scan(
    const int* __restrict__ mask, int* __restrict__ idx, int* __restrict__ nk)
{
  const int b = blockIdx.x, t = threadIdx.x;
  __shared__ int sc[256];
  int m[8]; int c = 0;
#pragma unroll
  for(int r = 0; r < 8; ++r){ m[r] = mask[b * 2048 + t * 8 + r]; c += (m[r] != 0); }
  sc[t] = c;
  __syncthreads();
  for(int s = 1; s < 256; s <<= 1){
    int v = (t >= s) ? sc[t - s] : 0;
    __syncthreads();
    sc[t] += v;
    __syncthreads();
  }
  int pos = sc[t] - c;            // exclusive prefix
  int total = sc[255];
#pragma unroll
  for(int r = 0; r < 8; ++r) if(m[r]) idx[b * 2048 + pos++] = t * 8 + r;
  int pend = (total + 127) & ~127;
  for(int p = total + t; p < pend; p += 256) idx[b * 2048 + p] = 0;
  if(t == 0) nk[b] = total;
}

// ---------------- GEMM: C = A @ B^T (+bias), A[M][K], B[N][K] ----------------
// Single-buffer K-loop (R9-proven). SWAPG: M-tile = blockIdx.x (XCD co-location
// of same-A-panel blocks). GATHER: 0 none, 1 = A f32 rows via idx, 2 = B f32
// rows via idx (per-batch compacted; fully-past blocks exit).
template<int MODE, bool AF32, bool BF32, int GATHER, bool SWAPG>
__global__ __launch_bounds__(256) void gemm_bt(
    const void* __restrict__ Ap, const void* __restrict__ Bp,
    const float* __restrict__ bias, void* __restrict__ outp,
    int M, int N, int K, float scale,
    const int* __restrict__ gidx, const int* __restrict__ nkarr)
{
  __shared__ __align__(16) unsigned short As[128 * 64];
  __shared__ __align__(16) unsigned short Bs[128 * 64];
  const int tid = threadIdx.x;
  const int gx = SWAPG ? blockIdx.y : blockIdx.x;  // N-tile
  const int gy = SWAPG ? blockIdx.x : blockIdx.y;  // M-tile
  const int w = tid >> 6, l = tid & 63, g = l >> 4, l15 = l & 15;
  const int wm = w >> 1, wn = w & 1;
  const int xsw = ((l & 7) ^ (l >> 3)) << 3;
  const int ch = tid & 7, srow = tid >> 3;

  int ia[4];                                        // gathered row indices
  int gb = 0;
  if constexpr(GATHER != 0){
    const int tilerow = (GATHER == 1) ? gy : gx;
    gb = (tilerow * 128) >> 11;
    const int j0 = (tilerow * 128) & 2047;
    const int total = nkarr[gb];
    if(j0 >= ((total + 127) & ~127)) return;        // uniform exit, pre-barrier
#pragma unroll
    for(int i = 0; i < 4; ++i)
      ia[i] = gidx[gb * 2048 + j0 + srow + i * 32];
  }

  f32x4 acc[4][4];
#pragma unroll
  for(int a = 0; a < 4; ++a)
#pragma unroll
    for(int b = 0; b < 4; ++b) acc[a][b] = (f32x4){0.f,0.f,0.f,0.f};

  const int nkt = K >> 6;
  for(int kt = 0; kt < nkt; ++kt){
    __syncthreads();
    if constexpr(AF32){
#pragma unroll
      for(int i = 0; i < 4; ++i){
        int row = srow + i * 32;
        const float* src;
        if constexpr(GATHER == 1)
          src = (const float*)Ap + ((size_t)gb * 2048 + ia[i]) * K + kt * 64 + ch * 8;
        else
          src = (const float*)Ap + (size_t)(gy * 128 + row) * K + kt * 64 + ch * 8;
        us8 va = ld_cvt_f32x8(src);
        *(us8*)&As[row * 64 + ((ch * 8) ^ ((row & 7) << 3))] = va;
      }
    } else {
      const unsigned short* Ab = (const unsigned short*)Ap;
#pragma unroll
      for(int j = 0; j < 4; ++j)
        gll16(Ab + (size_t)(gy * 128 + (w << 5) + (j << 3) + (l >> 3)) * K + kt * 64 + xsw,
              &As[((w << 5) + (j << 3)) << 6]);
    }
    if constexpr(BF32){
#pragma unroll
      for(int i = 0; i < 4; ++i){
        int row = srow + i * 32;
        const float* src;
        if constexpr(GATHER == 2)
          src = (const float*)Bp + ((size_t)gb * 2048 + ia[i]) * K + kt * 64 + ch * 8;
        else
          src = (const float*)Bp + (size_t)(gx * 128 + row) * K + kt * 64 + ch * 8;
        us8 vb = ld_cvt_f32x8(src);
        *(us8*)&Bs[row * 64 + ((ch * 8) ^ ((row & 7) << 3))] = vb;
      }
    } else {
      const unsigned short* Bb = (const unsigned short*)Bp;
#pragma unroll
      for(int j = 0; j < 4; ++j)
        gll16(Bb + (size_t)(gx * 128 + (w << 5) + (j << 3) + (l >> 3)) * K + kt * 64 + xsw,
              &Bs[((w << 5) + (j << 3)) << 6]);
    }
    if constexpr(!(AF32 && BF32))
      asm volatile("s_waitcnt vmcnt(0)" ::: "memory");
    __syncthreads();
#pragma unroll
    for(int kk = 0; kk < 2; ++kk){
      bf16x8 af[4], bg[4];
#pragma unroll
      for(int mi = 0; mi < 4; ++mi){
        int row = wm * 64 + mi * 16 + l15;
        af[mi] = ld_frag(&As[row * 64 + ((kk * 32 + g * 8) ^ ((row & 7) << 3))]);
      }
#pragma unroll
      for(int ni = 0; ni < 4; ++ni){
        int row = wn * 64 + ni * 16 + l15;
        bg[ni] = ld_frag(&Bs[row * 64 + ((kk * 32 + g * 8) ^ ((row & 7) << 3))]);
      }
#pragma unroll
      for(int mi = 0; mi < 4; ++mi)
#pragma unroll
        for(int ni = 0; ni < 4; ++ni)
          acc[mi][ni] = __builtin_amdgcn_mfma_f32_16x16x32_bf16(af[mi], bg[ni], acc[mi][ni], 0, 0, 0);
    }
  }

  // epilogue
#pragma unroll
  for(int mi = 0; mi < 4; ++mi)
#pragma unroll
    for(int ni = 0; ni < 4; ++ni){
      int gmb = gy * 128 + wm * 64 + mi * 16 + g * 4;
      int gn  = gx * 128 + wn * 64 + ni * 16 + l15;
#pragma unroll
      for(int r = 0; r < 4; ++r){
        int gm = gmb + r;
        float v = acc[mi][ni][r];
        if(MODE == 0){
          v = (v + bias[gn]) * scale;
          int b = gm >> 11, s = gm & 2047, h = gn >> 6, dh = gn & 63;
          ((unsigned short*)outp)[(size_t)(((b << 4) + h) * 2048 + s) * 64 + dh] = f2bf(v);
        } else if(MODE == 1){
          v = v + bias[gm];
          int h = gm >> 6, dh = gm & 63, b = gn >> 11, s = gn & 2047;
          ((unsigned short*)outp)[(size_t)(((b << 4) + h) * 64 + dh) * 2048 + s] = f2bf(v);
        } else {
          v = v + bias[gn];
          ((float*)outp)[(size_t)gm * N + gn] = v;
        }
      }
    }
}

// ---------------- Flash attention over compacted keys (unchanged from R9) ----------------
__global__ __launch_bounds__(256) void attn_kernel(
    const unsigned short* __restrict__ q, const unsigned short* __restrict__ ksc,
    const unsigned short* __restrict__ vTc, const int* __restrict__ nk,
    unsigned short* __restrict__ ctx)
{
  __shared__ __align__(16) unsigned short KsB[2][64 * 64];
  __shared__ __align__(16) unsigned short VtB[2][64 * 64];
  __shared__ __align__(16) unsigned short Ps[4][16 * 64];

  const int qt = blockIdx.x;
  const int bh = blockIdx.y;
  const int b  = bh >> 4, h = bh & 15;
  const int tid = threadIdx.x;
  const int w = tid >> 6, l = tid & 63, g = l >> 4, l15 = l & 15;
  const int rl = l >> 3, c8 = l & 7;

  const int nkb = nk[b];
  const int nt = (nkb + 63) >> 6;

  const unsigned short* qbase = q + ((size_t)(bh * 2048 + qt * 64 + w * 16 + l15)) * 64;
  bf16x8 bq[2];
  bq[0] = ld_frag(qbase + g * 8);
  bq[1] = ld_frag(qbase + 32 + g * 8);

  const unsigned short* kbase = ksc + (size_t)bh * 2048 * 64;
  const unsigned short* vbase = vTc + (size_t)bh * 64 * 2048;

  const unsigned short* kg0 = kbase + (size_t)(w * 16 + rl) * 64 + c8 * 8;
  const unsigned short* vg0 = vbase + (size_t)(w * 16 + rl) * 2048 + c8 * 8;
  const int lo0 = (w * 16 + rl) * 64 + ((c8 ^ rl) << 3);
  const int lo1 = lo0 + 8 * 64;

  us8 kr0, kr1, vr0, vr1;
#define LOAD_T(kt_) do{                                        \
    kr0 = *(const us8*)(kg0 + (size_t)(kt_) * 4096);           \
    kr1 = *(const us8*)(kg0 + (size_t)(kt_) * 4096 + 512);     \
    vr0 = *(const us8*)(vg0 + (size_t)(kt_) * 64);             \
    vr1 = *(const us8*)(vg0 + (size_t)(kt_) * 64 + 8 * 2048);  \
  }while(0)
#define WRITE_T(bb_) do{                                       \
    *(us8*)&KsB[bb_][lo0] = kr0;                               \
    *(us8*)&KsB[bb_][lo1] = kr1;                               \
    *(us8*)&VtB[bb_][lo0] = vr0;                               \
    *(us8*)&VtB[bb_][lo1] = vr1;                               \
  }while(0)

  f32x4 acc[4];
#pragma unroll
  for(int mi = 0; mi < 4; ++mi) acc[mi] = (f32x4){0.f,0.f,0.f,0.f};
  float ll = 0.f;

  LOAD_T(0);
  WRITE_T(0);
  __syncthreads();

  for(int kt = 0; kt < nt; ++kt){
    const int bb = kt & 1;
    if(kt + 1 < nt) LOAD_T(kt + 1);

    f32x4 sa[4];
#pragma unroll
    for(int mi = 0; mi < 4; ++mi) sa[mi] = (f32x4){0.f,0.f,0.f,0.f};
#pragma unroll
    for(int kk = 0; kk < 2; ++kk){
#pragma unroll
      for(int mi = 0; mi < 4; ++mi){
        int row = mi * 16 + l15;
        bf16x8 af = ld_frag(&KsB[bb][row * 64 + ((kk * 32 + g * 8) ^ ((row & 7) << 3))]);
        sa[mi] = __builtin_amdgcn_mfma_f32_16x16x32_bf16(af, bq[kk], sa[mi], 0, 0, 0);
      }
    }

    float p[4][4];
    if((kt + 1) * 64 <= nkb){
#pragma unroll
      for(int mi = 0; mi < 4; ++mi)
#pragma unroll
        for(int r = 0; r < 4; ++r){
          p[mi][r] = __builtin_amdgcn_exp2f(sa[mi][r]);
          ll += p[mi][r];
        }
    } else {
      int kb0 = kt * 64 + g * 4;
#pragma unroll
      for(int mi = 0; mi < 4; ++mi)
#pragma unroll
        for(int r = 0; r < 4; ++r){
          float e = __builtin_amdgcn_exp2f(sa[mi][r]);
          p[mi][r] = (kb0 + mi * 16 + r < nkb) ? e : 0.f;
          ll += p[mi][r];
        }
    }

#pragma unroll
    for(int mi = 0; mi < 4; ++mi){
      unsigned d0, d1;
      asm("v_cvt_pk_bf16_f32 %0, %1, %2" : "=v"(d0) : "v"(p[mi][0]), "v"(p[mi][1]));
      asm("v_cvt_pk_bf16_f32 %0, %1, %2" : "=v"(d1) : "v"(p[mi][2]), "v"(p[mi][3]));
      u32x2 dd = {d0, d1};
      *(u32x2*)&Ps[w][l15 * 64 + ((mi * 16 + g * 4) ^ ((l15 & 7) << 3))] = dd;
    }

#pragma unroll
    for(int kk = 0; kk < 2; ++kk){
      bf16x8 pb = ld_frag(&Ps[w][l15 * 64 + ((kk * 32 + g * 8) ^ ((l15 & 7) << 3))]);
#pragma unroll
      for(int mi = 0; mi < 4; ++mi){
        int row = mi * 16 + l15;
        bf16x8 av = ld_frag(&VtB[bb][row * 64 + ((kk * 32 + g * 8) ^ ((row & 7) << 3))]);
        acc[mi] = __builtin_amdgcn_mfma_f32_16x16x32_bf16(av, pb, acc[mi], 0, 0, 0);
      }
    }

    if(kt + 1 < nt) WRITE_T(bb ^ 1);
    __syncthreads();
  }

  ll += __shfl_xor(ll, 16);
  ll += __shfl_xor(ll, 32);
  float inv = 1.0f / ll;

  {
    int qrow = w * 16 + l15;
#pragma unroll
    for(int mi = 0; mi < 4; ++mi){
      us4 o;
#pragma unroll
      for(int r = 0; r < 4; ++r) o[r] = f2bf(acc[mi][r] * inv);
      *(us4*)&KsB[0][qrow * 64 + ((mi * 16 + g * 4) ^ ((qrow & 7) << 3))] = o;
    }
  }
  __syncthreads();
  {
    int qrow = tid >> 2, part = tid & 3;
    us8 v0 = *(const us8*)&KsB[0][qrow * 64 + ((part * 16)     ^ ((qrow & 7) << 3))];
    us8 v1 = *(const us8*)&KsB[0][qrow * 64 + ((part * 16 + 8) ^ ((qrow & 7) << 3))];
    size_t orow = ((size_t)b * 2048 + qt * 64 + qrow) * 1024 + h * 64 + part * 16;
    *(us8*)&ctx[orow] = v0;
    *(us8*)&ctx[orow + 8] = v1;
  }
#undef LOAD_T
#undef WRITE_T
}

// ---------------- launch ----------------
extern "C" void kernel_launch(void* const* d_in, const int* in_sizes, int n_in,
                              void* d_out, int out_size, void* d_ws, size_t ws_size,
                              hipStream_t stream) {
  const float* Qf = (const float*)d_in[0];
  const float* Kf = (const float*)d_in[1];
  const float* Vf = (const float*)d_in[2];
  const int*   Mk = (const int*)d_in[3];
  const float* Wq = (const float*)d_in[4];
  const float* bq = (const float*)d_in[5];
  const float* Wk = (const float*)d_in[6];
  const float* bk = (const float*)d_in[7];
  const float* Wv = (const float*)d_in[8];
  const float* bv = (const float*)d_in[9];
  const float* Wo = (const float*)d_in[10];
  const float* bo = (const float*)d_in[11];

  const size_t MB = 1u << 20;
  char* ws = (char*)d_ws;
  unsigned short* Wqb = (unsigned short*)(ws + 0 * MB);
  unsigned short* Wkb = (unsigned short*)(ws + 2 * MB);
  unsigned short* Wvb = (unsigned short*)(ws + 4 * MB);
  unsigned short* Wob = (unsigned short*)(ws + 6 * MB);
  unsigned short* qs  = (unsigned short*)(ws + 8 * MB);
  unsigned short* ksc = (unsigned short*)(ws + 24 * MB);
  unsigned short* vTc = (unsigned short*)(ws + 40 * MB);
  unsigned short* ctx = (unsigned short*)(ws + 56 * MB);
  int* idx = (int*)(ws + 72 * MB);
  int* nk  = (int*)(ws + 73 * MB);

  const int NW = 1024 * 1024;

  auto cvt = [&](const float* src, unsigned short* dst, int n){
    int n8 = n / 8;
    cvt_bf16<<<(n8 + 255) / 256, 256, 0, stream>>>(src, dst, n8);
  };
  cvt(Wq, Wqb, NW);
  cvt(Wk, Wkb, NW);
  cvt(Wv, Wvb, NW);
  cvt(Wo, Wob, NW);

  mask_scan<<<4, 256, 0, stream>>>(Mk, idx, nk);

  const float QSCALE = 0.125f * 1.4426950408889634f;  // 1/sqrt(d_head) * log2(e)
  dim3 blk(256);
  // Q-proj (full), SWAPG: grid (Mtiles=64, Ntiles=8)
  gemm_bt<0, true, false, 0, true><<<dim3(64, 8), blk, 0, stream>>>(
      Qf, Wqb, bq, qs, 8192, 1024, 1024, QSCALE, nullptr, nullptr);
  // K-proj over compacted keys (A rows gathered), SWAPG
  gemm_bt<0, true, false, 1, true><<<dim3(64, 8), blk, 0, stream>>>(
      Kf, Wkb, bk, ksc, 8192, 1024, 1024, 1.0f, idx, nk);
  // V-proj transposed (B = Vf is the big operand; grid (Ntiles=64, Mtiles=8)
  // already co-locates same-B-panel blocks)
  gemm_bt<1, false, true, 2, false><<<dim3(64, 8), blk, 0, stream>>>(
      Wvb, Vf, bv, vTc, 1024, 8192, 1024, 1.0f, idx, nk);
  // attention over compacted keys
  attn_kernel<<<dim3(32, 64), blk, 0, stream>>>(qs, ksc, vTc, nk, ctx);
  // output projection -> f32, SWAPG
  gemm_bt<2, false, false, 0, true><<<dim3(64, 8), blk, 0, stream>>>(
      ctx, Wob, bo, d_out, 8192, 1024, 1024, 1.0f, nullptr, nullptr);
}

// Round 12
// 182.248 us; speedup vs baseline: 1.1589x; 1.0296x over previous
//
#include <hip/hip_runtime.h>

// MHA: BS=4 SEQ=2048 D_MODEL=1024 H=16 DH=64
// R12 = R11 + (1) Q/K/V re-fused with XCD-correct placement: grid (64, 24),
// y = z*8+ny, linear = x + 64*y == x (mod 8) -> all same-activation-panel
// blocks (any z, any ny) on ONE XCD L2 (fixes R8's 396MB over-fetch).
// K/V blocks past compacted range exit early; their slots backfill with Q work.
// (2) attn: s_setprio(1) around MFMA clusters (T5).

typedef __attribute__((ext_vector_type(8))) unsigned short us8;
typedef __attribute__((ext_vector_type(4))) unsigned short us4;
typedef __attribute__((ext_vector_type(4))) int i4;
typedef __attribute__((ext_vector_type(4))) float f4;
typedef __attribute__((ext_vector_type(4))) float f32x4;
typedef __attribute__((ext_vector_type(8))) __bf16 bf16x8;
typedef __attribute__((ext_vector_type(2))) unsigned u32x2;
typedef __attribute__((ext_vector_type(4))) unsigned u32x4;

#define DEV static __device__ __forceinline__

DEV unsigned short f2bf(float f){
  unsigned u = __builtin_bit_cast(unsigned, f);
  u = (u + 0x7fffu + ((u >> 16) & 1u)) >> 16;
  return (unsigned short)u;
}

DEV bf16x8 ld_frag(const unsigned short* p){
  return __builtin_bit_cast(bf16x8, *(const us8*)p);
}

// async global->LDS, 16B per lane. LDS dest wave-uniform base + lane*16; global src per-lane.
DEV void gll16(const unsigned short* gsrc, unsigned short* ldst){
  __builtin_amdgcn_global_load_lds(
      (const __attribute__((address_space(1))) unsigned int*)gsrc,
      (__attribute__((address_space(3))) unsigned int*)ldst, 16, 0, 0);
}

// load 8 f32, convert to 8 bf16 via packed cvt (RNE)
DEV us8 ld_cvt_f32x8(const float* p){
  f4 v0 = *(const f4*)p;
  f4 v1 = *(const f4*)(p + 4);
  unsigned d0, d1, d2, d3;
  asm("v_cvt_pk_bf16_f32 %0, %1, %2" : "=v"(d0) : "v"(v0[0]), "v"(v0[1]));
  asm("v_cvt_pk_bf16_f32 %0, %1, %2" : "=v"(d1) : "v"(v0[2]), "v"(v0[3]));
  asm("v_cvt_pk_bf16_f32 %0, %1, %2" : "=v"(d2) : "v"(v1[0]), "v"(v1[1]));
  asm("v_cvt_pk_bf16_f32 %0, %1, %2" : "=v"(d3) : "v"(v1[2]), "v"(v1[3]));
  u32x4 u = {d0, d1, d2, d3};
  return __builtin_bit_cast(us8, u);
}

// ---------------- f32 -> bf16 conversion (weights only) ----------------
__global__ void cvt_bf16(const float* __restrict__ in, unsigned short* __restrict__ out, int n8){
  int i = blockIdx.x * 256 + threadIdx.x;
  if(i >= n8) return;
  *(us8*)(out + (size_t)i * 8) = ld_cvt_f32x8(in + (size_t)i * 8);
}

// ---------------- mask scan: compacted unmasked-key index list ----------------
__global__ __launch_bounds__(256) void mask_scan(
    const int* __restrict__ mask, int* __restrict__ idx, int* __restrict__ nk)
{
  const int b = blockIdx.x, t = threadIdx.x;
  __shared__ int sc[256];
  int m[8]; int c = 0;
#pragma unroll
  for(int r = 0; r < 8; ++r){ m[r] = mask[b * 2048 + t * 8 + r]; c += (m[r] != 0); }
  sc[t] = c;
  __syncthreads();
  for(int s = 1; s < 256; s <<= 1){
    int v = (t >= s) ? sc[t - s] : 0;
    __syncthreads();
    sc[t] += v;
    __syncthreads();
  }
  int pos = sc[t] - c;            // exclusive prefix
  int total = sc[255];
#pragma unroll
  for(int r = 0; r < 8; ++r) if(m[r]) idx[b * 2048 + pos++] = t * 8 + r;
  int pend = (total + 127) & ~127;
  for(int p = total + t; p < pend; p += 256) idx[b * 2048 + p] = 0;
  if(t == 0) nk[b] = total;
}

// ---------------- Fused Q/K/V projection, XCD-co-located ----------------
// grid (64, 24): x = activation tile (64), y = z*8+ny, z in {0:Q,1:K,2:V}.
// z=0: qs[..] = (Qf@Wq^T + bq)*qscale, split-head. z=1: ksc (gathered rows).
// z=2: vTc (b,h,dh,s) = Wv@Vf_gathered^T + bv.
__global__ __launch_bounds__(256) void qkv_proj(
    const float* __restrict__ Qf, const float* __restrict__ Kf, const float* __restrict__ Vf,
    const unsigned short* __restrict__ Wqb, const unsigned short* __restrict__ Wkb,
    const unsigned short* __restrict__ Wvb,
    const float* __restrict__ bq, const float* __restrict__ bk, const float* __restrict__ bv,
    unsigned short* __restrict__ qs, unsigned short* __restrict__ ksc,
    unsigned short* __restrict__ vTc, float qscale,
    const int* __restrict__ gidx, const int* __restrict__ nkarr)
{
  __shared__ __align__(16) unsigned short As[128 * 64];
  __shared__ __align__(16) unsigned short Bs[128 * 64];
  const int tid = threadIdx.x;
  const int x = blockIdx.x, z = blockIdx.y >> 3, ny = blockIdx.y & 7;
  const int w = tid >> 6, l = tid & 63, g = l >> 4, l15 = l & 15;
  const int wm = w >> 1, wn = w & 1;
  const int xsw = ((l & 7) ^ (l >> 3)) << 3;
  const int ch = tid & 7, srow = tid >> 3;

  // gather setup for compacted K/V rows
  int ia[4];
  int gb = 0;
  if(z >= 1){
    gb = (x * 128) >> 11;
    const int j0 = (x * 128) & 2047;
    if(j0 >= ((nkarr[gb] + 127) & ~127)) return;    // uniform exit, pre-barrier
#pragma unroll
    for(int i = 0; i < 4; ++i)
      ia[i] = gidx[gb * 2048 + j0 + srow + i * 32];
  }

  const float*          Af32 = (z == 0) ? Qf : Kf;  // z<2 activation
  const unsigned short* Wb   = (z == 0) ? Wqb : Wkb;

  f32x4 acc[4][4];
#pragma unroll
  for(int a = 0; a < 4; ++a)
#pragma unroll
    for(int b = 0; b < 4; ++b) acc[a][b] = (f32x4){0.f,0.f,0.f,0.f};

  for(int kt = 0; kt < 16; ++kt){
    __syncthreads();
    if(z < 2){
#pragma unroll
      for(int i = 0; i < 4; ++i){
        int row = srow + i * 32;
        const float* src = (z == 1)
          ? Af32 + ((size_t)gb * 2048 + ia[i]) * 1024 + kt * 64 + ch * 8
          : Af32 + (size_t)(x * 128 + row) * 1024 + kt * 64 + ch * 8;
        us8 va = ld_cvt_f32x8(src);
        *(us8*)&As[row * 64 + ((ch * 8) ^ ((row & 7) << 3))] = va;
      }
#pragma unroll
      for(int j = 0; j < 4; ++j)
        gll16(Wb + (size_t)(ny * 128 + (w << 5) + (j << 3) + (l >> 3)) * 1024 + kt * 64 + xsw,
              &Bs[((w << 5) + (j << 3)) << 6]);
    } else {
#pragma unroll
      for(int j = 0; j < 4; ++j)
        gll16(Wvb + (size_t)(ny * 128 + (w << 5) + (j << 3) + (l >> 3)) * 1024 + kt * 64 + xsw,
              &As[((w << 5) + (j << 3)) << 6]);
#pragma unroll
      for(int i = 0; i < 4; ++i){
        int row = srow + i * 32;
        const float* src = Vf + ((size_t)gb * 2048 + ia[i]) * 1024 + kt * 64 + ch * 8;
        us8 vb = ld_cvt_f32x8(src);
        *(us8*)&Bs[row * 64 + ((ch * 8) ^ ((row & 7) << 3))] = vb;
      }
    }
    asm volatile("s_waitcnt vmcnt(0)" ::: "memory");
    __syncthreads();
#pragma unroll
    for(int kk = 0; kk < 2; ++kk){
      bf16x8 af[4], bg[4];
#pragma unroll
      for(int mi = 0; mi < 4; ++mi){
        int row = wm * 64 + mi * 16 + l15;
        af[mi] = ld_frag(&As[row * 64 + ((kk * 32 + g * 8) ^ ((row & 7) << 3))]);
      }
#pragma unroll
      for(int ni = 0; ni < 4; ++ni){
        int row = wn * 64 + ni * 16 + l15;
        bg[ni] = ld_frag(&Bs[row * 64 + ((kk * 32 + g * 8) ^ ((row & 7) << 3))]);
      }
#pragma unroll
      for(int mi = 0; mi < 4; ++mi)
#pragma unroll
        for(int ni = 0; ni < 4; ++ni)
          acc[mi][ni] = __builtin_amdgcn_mfma_f32_16x16x32_bf16(af[mi], bg[ni], acc[mi][ni], 0, 0, 0);
    }
  }

  // epilogue
  if(z < 2){
    const float scale = (z == 0) ? qscale : 1.0f;
    const float* bias = (z == 0) ? bq : bk;
    unsigned short* out = (z == 0) ? qs : ksc;
#pragma unroll
    for(int mi = 0; mi < 4; ++mi)
#pragma unroll
      for(int ni = 0; ni < 4; ++ni){
        int gmb = x * 128 + wm * 64 + mi * 16 + g * 4;
        int gn  = ny * 128 + wn * 64 + ni * 16 + l15;
#pragma unroll
        for(int r = 0; r < 4; ++r){
          int gm = gmb + r;
          float v = (acc[mi][ni][r] + bias[gn]) * scale;
          int b = gm >> 11, s = gm & 2047, h = gn >> 6, dh = gn & 63;
          out[(size_t)(((b << 4) + h) * 2048 + s) * 64 + dh] = f2bf(v);
        }
      }
  } else {
#pragma unroll
    for(int mi = 0; mi < 4; ++mi)
#pragma unroll
      for(int ni = 0; ni < 4; ++ni){
        int gmb = ny * 128 + wm * 64 + mi * 16 + g * 4;   // d index
        int gn  = x * 128 + wn * 64 + ni * 16 + l15;      // compacted s index
#pragma unroll
        for(int r = 0; r < 4; ++r){
          int gm = gmb + r;
          float v = acc[mi][ni][r] + bv[gm];
          int h = gm >> 6, dh = gm & 63, b = gn >> 11, s = gn & 2047;
          vTc[(size_t)(((b << 4) + h) * 64 + dh) * 2048 + s] = f2bf(v);
        }
      }
  }
}

// ---------------- out-proj GEMM (R11 SWAPG form, bf16 operands) ----------------
__global__ __launch_bounds__(256) void gemm_out(
    const unsigned short* __restrict__ Ap, const unsigned short* __restrict__ Bp,
    const float* __restrict__ bias, float* __restrict__ outp, int K)
{
  __shared__ __align__(16) unsigned short As[128 * 64];
  __shared__ __align__(16) unsigned short Bs[128 * 64];
  const int tid = threadIdx.x;
  const int gy = blockIdx.x, gx = blockIdx.y;      // SWAPG: M-tile = x
  const int w = tid >> 6, l = tid & 63, g = l >> 4, l15 = l & 15;
  const int wm = w >> 1, wn = w & 1;
  const int xsw = ((l & 7) ^ (l >> 3)) << 3;

  f32x4 acc[4][4];
#pragma unroll
  for(int a = 0; a < 4; ++a)
#pragma unroll
    for(int b = 0; b < 4; ++b) acc[a][b] = (f32x4){0.f,0.f,0.f,0.f};

  const int nkt = K >> 6;
  for(int kt = 0; kt < nkt; ++kt){
    __syncthreads();
#pragma unroll
    for(int j = 0; j < 4; ++j)
      gll16(Ap + (size_t)(gy * 128 + (w << 5) + (j << 3) + (l >> 3)) * K + kt * 64 + xsw,
            &As[((w << 5) + (j << 3)) << 6]);
#pragma unroll
    for(int j = 0; j < 4; ++j)
      gll16(Bp + (size_t)(gx * 128 + (w << 5) + (j << 3) + (l >> 3)) * K + kt * 64 + xsw,
            &Bs[((w << 5) + (j << 3)) << 6]);
    asm volatile("s_waitcnt vmcnt(0)" ::: "memory");
    __syncthreads();
#pragma unroll
    for(int kk = 0; kk < 2; ++kk){
      bf16x8 af[4], bg[4];
#pragma unroll
      for(int mi = 0; mi < 4; ++mi){
        int row = wm * 64 + mi * 16 + l15;
        af[mi] = ld_frag(&As[row * 64 + ((kk * 32 + g * 8) ^ ((row & 7) << 3))]);
      }
#pragma unroll
      for(int ni = 0; ni < 4; ++ni){
        int row = wn * 64 + ni * 16 + l15;
        bg[ni] = ld_frag(&Bs[row * 64 + ((kk * 32 + g * 8) ^ ((row & 7) << 3))]);
      }
#pragma unroll
      for(int mi = 0; mi < 4; ++mi)
#pragma unroll
        for(int ni = 0; ni < 4; ++ni)
          acc[mi][ni] = __builtin_amdgcn_mfma_f32_16x16x32_bf16(af[mi], bg[ni], acc[mi][ni], 0, 0, 0);
    }
  }

#pragma unroll
  for(int mi = 0; mi < 4; ++mi)
#pragma unroll
    for(int ni = 0; ni < 4; ++ni){
      int gmb = gy * 128 + wm * 64 + mi * 16 + g * 4;
      int gn  = gx * 128 + wn * 64 + ni * 16 + l15;
#pragma unroll
      for(int r = 0; r < 4; ++r)
        outp[(size_t)(gmb + r) * 1024 + gn] = acc[mi][ni][r] + bias[gn];
    }
}

// ---------------- Flash attention over compacted keys (R9 + T5 setprio) ----------------
__global__ __launch_bounds__(256) void attn_kernel(
    const unsigned short* __restrict__ q, const unsigned short* __restrict__ ksc,
    const unsigned short* __restrict__ vTc, const int* __restrict__ nk,
    unsigned short* __restrict__ ctx)
{
  __shared__ __align__(16) unsigned short KsB[2][64 * 64];
  __shared__ __align__(16) unsigned short VtB[2][64 * 64];
  __shared__ __align__(16) unsigned short Ps[4][16 * 64];

  const int qt = blockIdx.x;
  const int bh = blockIdx.y;
  const int b  = bh >> 4, h = bh & 15;
  const int tid = threadIdx.x;
  const int w = tid >> 6, l = tid & 63, g = l >> 4, l15 = l & 15;
  const int rl = l >> 3, c8 = l & 7;

  const int nkb = nk[b];
  const int nt = (nkb + 63) >> 6;

  const unsigned short* qbase = q + ((size_t)(bh * 2048 + qt * 64 + w * 16 + l15)) * 64;
  bf16x8 bq[2];
  bq[0] = ld_frag(qbase + g * 8);
  bq[1] = ld_frag(qbase + 32 + g * 8);

  const unsigned short* kbase = ksc + (size_t)bh * 2048 * 64;
  const unsigned short* vbase = vTc + (size_t)bh * 64 * 2048;

  const unsigned short* kg0 = kbase + (size_t)(w * 16 + rl) * 64 + c8 * 8;
  const unsigned short* vg0 = vbase + (size_t)(w * 16 + rl) * 2048 + c8 * 8;
  const int lo0 = (w * 16 + rl) * 64 + ((c8 ^ rl) << 3);
  const int lo1 = lo0 + 8 * 64;

  us8 kr0, kr1, vr0, vr1;
#define LOAD_T(kt_) do{                                        \
    kr0 = *(const us8*)(kg0 + (size_t)(kt_) * 4096);           \
    kr1 = *(const us8*)(kg0 + (size_t)(kt_) * 4096 + 512);     \
    vr0 = *(const us8*)(vg0 + (size_t)(kt_) * 64);             \
    vr1 = *(const us8*)(vg0 + (size_t)(kt_) * 64 + 8 * 2048);  \
  }while(0)
#define WRITE_T(bb_) do{                                       \
    *(us8*)&KsB[bb_][lo0] = kr0;                               \
    *(us8*)&KsB[bb_][lo1] = kr1;                               \
    *(us8*)&VtB[bb_][lo0] = vr0;                               \
    *(us8*)&VtB[bb_][lo1] = vr1;                               \
  }while(0)

  f32x4 acc[4];
#pragma unroll
  for(int mi = 0; mi < 4; ++mi) acc[mi] = (f32x4){0.f,0.f,0.f,0.f};
  float ll = 0.f;

  LOAD_T(0);
  WRITE_T(0);
  __syncthreads();

  for(int kt = 0; kt < nt; ++kt){
    const int bb = kt & 1;
    if(kt + 1 < nt) LOAD_T(kt + 1);

    f32x4 sa[4];
#pragma unroll
    for(int mi = 0; mi < 4; ++mi) sa[mi] = (f32x4){0.f,0.f,0.f,0.f};
    __builtin_amdgcn_s_setprio(1);
#pragma unroll
    for(int kk = 0; kk < 2; ++kk){
#pragma unroll
      for(int mi = 0; mi < 4; ++mi){
        int row = mi * 16 + l15;
        bf16x8 af = ld_frag(&KsB[bb][row * 64 + ((kk * 32 + g * 8) ^ ((row & 7) << 3))]);
        sa[mi] = __builtin_amdgcn_mfma_f32_16x16x32_bf16(af, bq[kk], sa[mi], 0, 0, 0);
      }
    }
    __builtin_amdgcn_s_setprio(0);

    float p[4][4];
    if((kt + 1) * 64 <= nkb){
#pragma unroll
      for(int mi = 0; mi < 4; ++mi)
#pragma unroll
        for(int r = 0; r < 4; ++r){
          p[mi][r] = __builtin_amdgcn_exp2f(sa[mi][r]);
          ll += p[mi][r];
        }
    } else {
      int kb0 = kt * 64 + g * 4;
#pragma unroll
      for(int mi = 0; mi < 4; ++mi)
#pragma unroll
        for(int r = 0; r < 4; ++r){
          float e = __builtin_amdgcn_exp2f(sa[mi][r]);
          p[mi][r] = (kb0 + mi * 16 + r < nkb) ? e : 0.f;
          ll += p[mi][r];
        }
    }

#pragma unroll
    for(int mi = 0; mi < 4; ++mi){
      unsigned d0, d1;
      asm("v_cvt_pk_bf16_f32 %0, %1, %2" : "=v"(d0) : "v"(p[mi][0]), "v"(p[mi][1]));
      asm("v_cvt_pk_bf16_f32 %0, %1, %2" : "=v"(d1) : "v"(p[mi][2]), "v"(p[mi][3]));
      u32x2 dd = {d0, d1};
      *(u32x2*)&Ps[w][l15 * 64 + ((mi * 16 + g * 4) ^ ((l15 & 7) << 3))] = dd;
    }

    __builtin_amdgcn_s_setprio(1);
#pragma unroll
    for(int kk = 0; kk < 2; ++kk){
      bf16x8 pb = ld_frag(&Ps[w][l15 * 64 + ((kk * 32 + g * 8) ^ ((l15 & 7) << 3))]);
#pragma unroll
      for(int mi = 0; mi < 4; ++mi){
        int row = mi * 16 + l15;
        bf16x8 av = ld_frag(&VtB[bb][row * 64 + ((kk * 32 + g * 8) ^ ((row & 7) << 3))]);
        acc[mi] = __builtin_amdgcn_mfma_f32_16x16x32_bf16(av, pb, acc[mi], 0, 0, 0);
      }
    }
    __builtin_amdgcn_s_setprio(0);

    if(kt + 1 < nt) WRITE_T(bb ^ 1);
    __syncthreads();
  }

  ll += __shfl_xor(ll, 16);
  ll += __shfl_xor(ll, 32);
  float inv = 1.0f / ll;

  {
    int qrow = w * 16 + l15;
#pragma unroll
    for(int mi = 0; mi < 4; ++mi){
      us4 o;
#pragma unroll
      for(int r = 0; r < 4; ++r) o[r] = f2bf(acc[mi][r] * inv);
      *(us4*)&KsB[0][qrow * 64 + ((mi * 16 + g * 4) ^ ((qrow & 7) << 3))] = o;
    }
  }
  __syncthreads();
  {
    int qrow = tid >> 2, part = tid & 3;
    us8 v0 = *(const us8*)&KsB[0][qrow * 64 + ((part * 16)     ^ ((qrow & 7) << 3))];
    us8 v1 = *(const us8*)&KsB[0][qrow * 64 + ((part * 16 + 8) ^ ((qrow & 7) << 3))];
    size_t orow = ((size_t)b * 2048 + qt * 64 + qrow) * 1024 + h * 64 + part * 16;
    *(us8*)&ctx[orow] = v0;
    *(us8*)&ctx[orow + 8] = v1;
  }
#undef LOAD_T
#undef WRITE_T
}

// ---------------- launch ----------------
extern "C" void kernel_launch(void* const* d_in, const int* in_sizes, int n_in,
                              void* d_out, int out_size, void* d_ws, size_t ws_size,
                              hipStream_t stream) {
  const float* Qf = (const float*)d_in[0];
  const float* Kf = (const float*)d_in[1];
  const float* Vf = (const float*)d_in[2];
  const int*   Mk = (const int*)d_in[3];
  const float* Wq = (const float*)d_in[4];
  const float* bq = (const float*)d_in[5];
  const float* Wk = (const float*)d_in[6];
  const float* bk = (const float*)d_in[7];
  const float* Wv = (const float*)d_in[8];
  const float* bv = (const float*)d_in[9];
  const float* Wo = (const float*)d_in[10];
  const float* bo = (const float*)d_in[11];

  const size_t MB = 1u << 20;
  char* ws = (char*)d_ws;
  unsigned short* Wqb = (unsigned short*)(ws + 0 * MB);
  unsigned short* Wkb = (unsigned short*)(ws + 2 * MB);
  unsigned short* Wvb = (unsigned short*)(ws + 4 * MB);
  unsigned short* Wob = (unsigned short*)(ws + 6 * MB);
  unsigned short* qs  = (unsigned short*)(ws + 8 * MB);
  unsigned short* ksc = (unsigned short*)(ws + 24 * MB);
  unsigned short* vTc = (unsigned short*)(ws + 40 * MB);
  unsigned short* ctx = (unsigned short*)(ws + 56 * MB);
  int* idx = (int*)(ws + 72 * MB);
  int* nk  = (int*)(ws + 73 * MB);

  const int NW = 1024 * 1024;

  mask_scan<<<4, 256, 0, stream>>>(Mk, idx, nk);

  auto cvt = [&](const float* src, unsigned short* dst, int n){
    int n8 = n / 8;
    cvt_bf16<<<(n8 + 255) / 256, 256, 0, stream>>>(src, dst, n8);
  };
  cvt(Wq, Wqb, NW);
  cvt(Wk, Wkb, NW);
  cvt(Wv, Wvb, NW);
  cvt(Wo, Wob, NW);

  const float QSCALE = 0.125f * 1.4426950408889634f;  // 1/sqrt(d_head) * log2(e)
  dim3 blk(256);
  // fused Q/K/V, XCD-co-located: grid (64, 24)
  qkv_proj<<<dim3(64, 24), blk, 0, stream>>>(Qf, Kf, Vf, Wqb, Wkb, Wvb,
                                             bq, bk, bv, qs, ksc, vTc, QSCALE,
                                             idx, nk);
  // attention over compacted keys
  attn_kernel<<<dim3(32, 64), blk, 0, stream>>>(qs, ksc, vTc, nk, ctx);
  // output projection -> f32 (SWAPG grid)
  gemm_out<<<dim3(64, 8), blk, 0, stream>>>(ctx, Wob, bo, (float*)d_out, 1024);
}

// Round 13
// 175.032 us; speedup vs baseline: 1.2067x; 1.0412x over previous
//
#include <hip/hip_runtime.h>

// MHA: BS=4 SEQ=2048 D_MODEL=1024 H=16 DH=64
// R13 = R12 + (1) attn grid SWAPPED to (bh=64, qt=32): linear = bh + 64*qt
// == bh (mod 8) -> all 32 q-blocks sharing one (b,h)'s K/V land on ONE XCD;
// K/V panels (8 bh x 512KB = 4MB) stay in that XCD's L2, reused 32x.
// (2) 4 weight-cvt launches merged into one z-indexed dispatch.

typedef __attribute__((ext_vector_type(8))) unsigned short us8;
typedef __attribute__((ext_vector_type(4))) unsigned short us4;
typedef __attribute__((ext_vector_type(4))) int i4;
typedef __attribute__((ext_vector_type(4))) float f4;
typedef __attribute__((ext_vector_type(4))) float f32x4;
typedef __attribute__((ext_vector_type(8))) __bf16 bf16x8;
typedef __attribute__((ext_vector_type(2))) unsigned u32x2;
typedef __attribute__((ext_vector_type(4))) unsigned u32x4;

#define DEV static __device__ __forceinline__

DEV unsigned short f2bf(float f){
  unsigned u = __builtin_bit_cast(unsigned, f);
  u = (u + 0x7fffu + ((u >> 16) & 1u)) >> 16;
  return (unsigned short)u;
}

DEV bf16x8 ld_frag(const unsigned short* p){
  return __builtin_bit_cast(bf16x8, *(const us8*)p);
}

// async global->LDS, 16B per lane. LDS dest wave-uniform base + lane*16; global src per-lane.
DEV void gll16(const unsigned short* gsrc, unsigned short* ldst){
  __builtin_amdgcn_global_load_lds(
      (const __attribute__((address_space(1))) unsigned int*)gsrc,
      (__attribute__((address_space(3))) unsigned int*)ldst, 16, 0, 0);
}

// load 8 f32, convert to 8 bf16 via packed cvt (RNE)
DEV us8 ld_cvt_f32x8(const float* p){
  f4 v0 = *(const f4*)p;
  f4 v1 = *(const f4*)(p + 4);
  unsigned d0, d1, d2, d3;
  asm("v_cvt_pk_bf16_f32 %0, %1, %2" : "=v"(d0) : "v"(v0[0]), "v"(v0[1]));
  asm("v_cvt_pk_bf16_f32 %0, %1, %2" : "=v"(d1) : "v"(v0[2]), "v"(v0[3]));
  asm("v_cvt_pk_bf16_f32 %0, %1, %2" : "=v"(d2) : "v"(v1[0]), "v"(v1[1]));
  asm("v_cvt_pk_bf16_f32 %0, %1, %2" : "=v"(d3) : "v"(v1[2]), "v"(v1[3]));
  u32x4 u = {d0, d1, d2, d3};
  return __builtin_bit_cast(us8, u);
}

// ---------------- f32 -> bf16 conversion, 4 weights in one dispatch ----------------
__global__ void cvt_bf16x4(const float* __restrict__ w0, const float* __restrict__ w1,
                           const float* __restrict__ w2, const float* __restrict__ w3,
                           unsigned short* __restrict__ o0, unsigned short* __restrict__ o1,
                           unsigned short* __restrict__ o2, unsigned short* __restrict__ o3)
{
  const int z = blockIdx.y;
  const float* src = (z == 0) ? w0 : (z == 1) ? w1 : (z == 2) ? w2 : w3;
  unsigned short* dst = (z == 0) ? o0 : (z == 1) ? o1 : (z == 2) ? o2 : o3;
  int i = blockIdx.x * 256 + threadIdx.x;   // 512 blocks x 256 t x 8 elems = 1M
  *(us8*)(dst + (size_t)i * 8) = ld_cvt_f32x8(src + (size_t)i * 8);
}

// ---------------- mask scan: compacted unmasked-key index list ----------------
__global__ __launch_bounds__(256) void mask_scan(
    const int* __restrict__ mask, int* __restrict__ idx, int* __restrict__ nk)
{
  const int b = blockIdx.x, t = threadIdx.x;
  __shared__ int sc[256];
  int m[8]; int c = 0;
#pragma unroll
  for(int r = 0; r < 8; ++r){ m[r] = mask[b * 2048 + t * 8 + r]; c += (m[r] != 0); }
  sc[t] = c;
  __syncthreads();
  for(int s = 1; s < 256; s <<= 1){
    int v = (t >= s) ? sc[t - s] : 0;
    __syncthreads();
    sc[t] += v;
    __syncthreads();
  }
  int pos = sc[t] - c;            // exclusive prefix
  int total = sc[255];
#pragma unroll
  for(int r = 0; r < 8; ++r) if(m[r]) idx[b * 2048 + pos++] = t * 8 + r;
  int pend = (total + 127) & ~127;
  for(int p = total + t; p < pend; p += 256) idx[b * 2048 + p] = 0;
  if(t == 0) nk[b] = total;
}

// ---------------- Fused Q/K/V projection, XCD-co-located (R12-proven) ----------------
__global__ __launch_bounds__(256) void qkv_proj(
    const float* __restrict__ Qf, const float* __restrict__ Kf, const float* __restrict__ Vf,
    const unsigned short* __restrict__ Wqb, const unsigned short* __restrict__ Wkb,
    const unsigned short* __restrict__ Wvb,
    const float* __restrict__ bq, const float* __restrict__ bk, const float* __restrict__ bv,
    unsigned short* __restrict__ qs, unsigned short* __restrict__ ksc,
    unsigned short* __restrict__ vTc, float qscale,
    const int* __restrict__ gidx, const int* __restrict__ nkarr)
{
  __shared__ __align__(16) unsigned short As[128 * 64];
  __shared__ __align__(16) unsigned short Bs[128 * 64];
  const int tid = threadIdx.x;
  const int x = blockIdx.x, z = blockIdx.y >> 3, ny = blockIdx.y & 7;
  const int w = tid >> 6, l = tid & 63, g = l >> 4, l15 = l & 15;
  const int wm = w >> 1, wn = w & 1;
  const int xsw = ((l & 7) ^ (l >> 3)) << 3;
  const int ch = tid & 7, srow = tid >> 3;

  int ia[4];
  int gb = 0;
  if(z >= 1){
    gb = (x * 128) >> 11;
    const int j0 = (x * 128) & 2047;
    if(j0 >= ((nkarr[gb] + 127) & ~127)) return;    // uniform exit, pre-barrier
#pragma unroll
    for(int i = 0; i < 4; ++i)
      ia[i] = gidx[gb * 2048 + j0 + srow + i * 32];
  }

  const float*          Af32 = (z == 0) ? Qf : Kf;
  const unsigned short* Wb   = (z == 0) ? Wqb : Wkb;

  f32x4 acc[4][4];
#pragma unroll
  for(int a = 0; a < 4; ++a)
#pragma unroll
    for(int b = 0; b < 4; ++b) acc[a][b] = (f32x4){0.f,0.f,0.f,0.f};

  for(int kt = 0; kt < 16; ++kt){
    __syncthreads();
    if(z < 2){
#pragma unroll
      for(int i = 0; i < 4; ++i){
        int row = srow + i * 32;
        const float* src = (z == 1)
          ? Af32 + ((size_t)gb * 2048 + ia[i]) * 1024 + kt * 64 + ch * 8
          : Af32 + (size_t)(x * 128 + row) * 1024 + kt * 64 + ch * 8;
        us8 va = ld_cvt_f32x8(src);
        *(us8*)&As[row * 64 + ((ch * 8) ^ ((row & 7) << 3))] = va;
      }
#pragma unroll
      for(int j = 0; j < 4; ++j)
        gll16(Wb + (size_t)(ny * 128 + (w << 5) + (j << 3) + (l >> 3)) * 1024 + kt * 64 + xsw,
              &Bs[((w << 5) + (j << 3)) << 6]);
    } else {
#pragma unroll
      for(int j = 0; j < 4; ++j)
        gll16(Wvb + (size_t)(ny * 128 + (w << 5) + (j << 3) + (l >> 3)) * 1024 + kt * 64 + xsw,
              &As[((w << 5) + (j << 3)) << 6]);
#pragma unroll
      for(int i = 0; i < 4; ++i){
        int row = srow + i * 32;
        const float* src = Vf + ((size_t)gb * 2048 + ia[i]) * 1024 + kt * 64 + ch * 8;
        us8 vb = ld_cvt_f32x8(src);
        *(us8*)&Bs[row * 64 + ((ch * 8) ^ ((row & 7) << 3))] = vb;
      }
    }
    asm volatile("s_waitcnt vmcnt(0)" ::: "memory");
    __syncthreads();
#pragma unroll
    for(int kk = 0; kk < 2; ++kk){
      bf16x8 af[4], bg[4];
#pragma unroll
      for(int mi = 0; mi < 4; ++mi){
        int row = wm * 64 + mi * 16 + l15;
        af[mi] = ld_frag(&As[row * 64 + ((kk * 32 + g * 8) ^ ((row & 7) << 3))]);
      }
#pragma unroll
      for(int ni = 0; ni < 4; ++ni){
        int row = wn * 64 + ni * 16 + l15;
        bg[ni] = ld_frag(&Bs[row * 64 + ((kk * 32 + g * 8) ^ ((row & 7) << 3))]);
      }
#pragma unroll
      for(int mi = 0; mi < 4; ++mi)
#pragma unroll
        for(int ni = 0; ni < 4; ++ni)
          acc[mi][ni] = __builtin_amdgcn_mfma_f32_16x16x32_bf16(af[mi], bg[ni], acc[mi][ni], 0, 0, 0);
    }
  }

  if(z < 2){
    const float scale = (z == 0) ? qscale : 1.0f;
    const float* bias = (z == 0) ? bq : bk;
    unsigned short* out = (z == 0) ? qs : ksc;
#pragma unroll
    for(int mi = 0; mi < 4; ++mi)
#pragma unroll
      for(int ni = 0; ni < 4; ++ni){
        int gmb = x * 128 + wm * 64 + mi * 16 + g * 4;
        int gn  = ny * 128 + wn * 64 + ni * 16 + l15;
#pragma unroll
        for(int r = 0; r < 4; ++r){
          int gm = gmb + r;
          float v = (acc[mi][ni][r] + bias[gn]) * scale;
          int b = gm >> 11, s = gm & 2047, h = gn >> 6, dh = gn & 63;
          out[(size_t)(((b << 4) + h) * 2048 + s) * 64 + dh] = f2bf(v);
        }
      }
  } else {
#pragma unroll
    for(int mi = 0; mi < 4; ++mi)
#pragma unroll
      for(int ni = 0; ni < 4; ++ni){
        int gmb = ny * 128 + wm * 64 + mi * 16 + g * 4;   // d index
        int gn  = x * 128 + wn * 64 + ni * 16 + l15;      // compacted s index
#pragma unroll
        for(int r = 0; r < 4; ++r){
          int gm = gmb + r;
          float v = acc[mi][ni][r] + bv[gm];
          int h = gm >> 6, dh = gm & 63, b = gn >> 11, s = gn & 2047;
          vTc[(size_t)(((b << 4) + h) * 64 + dh) * 2048 + s] = f2bf(v);
        }
      }
  }
}

// ---------------- out-proj GEMM (SWAPG, bf16 operands) ----------------
__global__ __launch_bounds__(256) void gemm_out(
    const unsigned short* __restrict__ Ap, const unsigned short* __restrict__ Bp,
    const float* __restrict__ bias, float* __restrict__ outp, int K)
{
  __shared__ __align__(16) unsigned short As[128 * 64];
  __shared__ __align__(16) unsigned short Bs[128 * 64];
  const int tid = threadIdx.x;
  const int gy = blockIdx.x, gx = blockIdx.y;      // SWAPG: M-tile = x
  const int w = tid >> 6, l = tid & 63, g = l >> 4, l15 = l & 15;
  const int wm = w >> 1, wn = w & 1;
  const int xsw = ((l & 7) ^ (l >> 3)) << 3;

  f32x4 acc[4][4];
#pragma unroll
  for(int a = 0; a < 4; ++a)
#pragma unroll
    for(int b = 0; b < 4; ++b) acc[a][b] = (f32x4){0.f,0.f,0.f,0.f};

  const int nkt = K >> 6;
  for(int kt = 0; kt < nkt; ++kt){
    __syncthreads();
#pragma unroll
    for(int j = 0; j < 4; ++j)
      gll16(Ap + (size_t)(gy * 128 + (w << 5) + (j << 3) + (l >> 3)) * K + kt * 64 + xsw,
            &As[((w << 5) + (j << 3)) << 6]);
#pragma unroll
    for(int j = 0; j < 4; ++j)
      gll16(Bp + (size_t)(gx * 128 + (w << 5) + (j << 3) + (l >> 3)) * K + kt * 64 + xsw,
            &Bs[((w << 5) + (j << 3)) << 6]);
    asm volatile("s_waitcnt vmcnt(0)" ::: "memory");
    __syncthreads();
#pragma unroll
    for(int kk = 0; kk < 2; ++kk){
      bf16x8 af[4], bg[4];
#pragma unroll
      for(int mi = 0; mi < 4; ++mi){
        int row = wm * 64 + mi * 16 + l15;
        af[mi] = ld_frag(&As[row * 64 + ((kk * 32 + g * 8) ^ ((row & 7) << 3))]);
      }
#pragma unroll
      for(int ni = 0; ni < 4; ++ni){
        int row = wn * 64 + ni * 16 + l15;
        bg[ni] = ld_frag(&Bs[row * 64 + ((kk * 32 + g * 8) ^ ((row & 7) << 3))]);
      }
#pragma unroll
      for(int mi = 0; mi < 4; ++mi)
#pragma unroll
        for(int ni = 0; ni < 4; ++ni)
          acc[mi][ni] = __builtin_amdgcn_mfma_f32_16x16x32_bf16(af[mi], bg[ni], acc[mi][ni], 0, 0, 0);
    }
  }

#pragma unroll
  for(int mi = 0; mi < 4; ++mi)
#pragma unroll
    for(int ni = 0; ni < 4; ++ni){
      int gmb = gy * 128 + wm * 64 + mi * 16 + g * 4;
      int gn  = gx * 128 + wn * 64 + ni * 16 + l15;
#pragma unroll
      for(int r = 0; r < 4; ++r)
        outp[(size_t)(gmb + r) * 1024 + gn] = acc[mi][ni][r] + bias[gn];
    }
}

// ---------------- Flash attention, bh-major grid (XCD co-location) ----------------
// grid (bh=64, qt=32): linear = bh + 64*qt == bh (mod 8) -> same-bh blocks on
// one XCD; that XCD's L2 holds its 8 bh's K/V (4MB), reused by 32 q-blocks.
__global__ __launch_bounds__(256) void attn_kernel(
    const unsigned short* __restrict__ q, const unsigned short* __restrict__ ksc,
    const unsigned short* __restrict__ vTc, const int* __restrict__ nk,
    unsigned short* __restrict__ ctx)
{
  __shared__ __align__(16) unsigned short KsB[2][64 * 64];
  __shared__ __align__(16) unsigned short VtB[2][64 * 64];
  __shared__ __align__(16) unsigned short Ps[4][16 * 64];

  const int bh = blockIdx.x;            // SWAPPED: bh fastest -> XCD co-location
  const int qt = blockIdx.y;
  const int b  = bh >> 4, h = bh & 15;
  const int tid = threadIdx.x;
  const int w = tid >> 6, l = tid & 63, g = l >> 4, l15 = l & 15;
  const int rl = l >> 3, c8 = l & 7;

  const int nkb = nk[b];
  const int nt = (nkb + 63) >> 6;

  const unsigned short* qbase = q + ((size_t)(bh * 2048 + qt * 64 + w * 16 + l15)) * 64;
  bf16x8 bq[2];
  bq[0] = ld_frag(qbase + g * 8);
  bq[1] = ld_frag(qbase + 32 + g * 8);

  const unsigned short* kbase = ksc + (size_t)bh * 2048 * 64;
  const unsigned short* vbase = vTc + (size_t)bh * 64 * 2048;

  const unsigned short* kg0 = kbase + (size_t)(w * 16 + rl) * 64 + c8 * 8;
  const unsigned short* vg0 = vbase + (size_t)(w * 16 + rl) * 2048 + c8 * 8;
  const int lo0 = (w * 16 + rl) * 64 + ((c8 ^ rl) << 3);
  const int lo1 = lo0 + 8 * 64;

  us8 kr0, kr1, vr0, vr1;
#define LOAD_T(kt_) do{                                        \
    kr0 = *(const us8*)(kg0 + (size_t)(kt_) * 4096);           \
    kr1 = *(const us8*)(kg0 + (size_t)(kt_) * 4096 + 512);     \
    vr0 = *(const us8*)(vg0 + (size_t)(kt_) * 64);             \
    vr1 = *(const us8*)(vg0 + (size_t)(kt_) * 64 + 8 * 2048);  \
  }while(0)
#define WRITE_T(bb_) do{                                       \
    *(us8*)&KsB[bb_][lo0] = kr0;                               \
    *(us8*)&KsB[bb_][lo1] = kr1;                               \
    *(us8*)&VtB[bb_][lo0] = vr0;                               \
    *(us8*)&VtB[bb_][lo1] = vr1;                               \
  }while(0)

  f32x4 acc[4];
#pragma unroll
  for(int mi = 0; mi < 4; ++mi) acc[mi] = (f32x4){0.f,0.f,0.f,0.f};
  float ll = 0.f;

  LOAD_T(0);
  WRITE_T(0);
  __syncthreads();

  for(int kt = 0; kt < nt; ++kt){
    const int bb = kt & 1;
    if(kt + 1 < nt) LOAD_T(kt + 1);

    f32x4 sa[4];
#pragma unroll
    for(int mi = 0; mi < 4; ++mi) sa[mi] = (f32x4){0.f,0.f,0.f,0.f};
    __builtin_amdgcn_s_setprio(1);
#pragma unroll
    for(int kk = 0; kk < 2; ++kk){
#pragma unroll
      for(int mi = 0; mi < 4; ++mi){
        int row = mi * 16 + l15;
        bf16x8 af = ld_frag(&KsB[bb][row * 64 + ((kk * 32 + g * 8) ^ ((row & 7) << 3))]);
        sa[mi] = __builtin_amdgcn_mfma_f32_16x16x32_bf16(af, bq[kk], sa[mi], 0, 0, 0);
      }
    }
    __builtin_amdgcn_s_setprio(0);

    float p[4][4];
    if((kt + 1) * 64 <= nkb){
#pragma unroll
      for(int mi = 0; mi < 4; ++mi)
#pragma unroll
        for(int r = 0; r < 4; ++r){
          p[mi][r] = __builtin_amdgcn_exp2f(sa[mi][r]);
          ll += p[mi][r];
        }
    } else {
      int kb0 = kt * 64 + g * 4;
#pragma unroll
      for(int mi = 0; mi < 4; ++mi)
#pragma unroll
        for(int r = 0; r < 4; ++r){
          float e = __builtin_amdgcn_exp2f(sa[mi][r]);
          p[mi][r] = (kb0 + mi * 16 + r < nkb) ? e : 0.f;
          ll += p[mi][r];
        }
    }

#pragma unroll
    for(int mi = 0; mi < 4; ++mi){
      unsigned d0, d1;
      asm("v_cvt_pk_bf16_f32 %0, %1, %2" : "=v"(d0) : "v"(p[mi][0]), "v"(p[mi][1]));
      asm("v_cvt_pk_bf16_f32 %0, %1, %2" : "=v"(d1) : "v"(p[mi][2]), "v"(p[mi][3]));
      u32x2 dd = {d0, d1};
      *(u32x2*)&Ps[w][l15 * 64 + ((mi * 16 + g * 4) ^ ((l15 & 7) << 3))] = dd;
    }

    __builtin_amdgcn_s_setprio(1);
#pragma unroll
    for(int kk = 0; kk < 2; ++kk){
      bf16x8 pb = ld_frag(&Ps[w][l15 * 64 + ((kk * 32 + g * 8) ^ ((l15 & 7) << 3))]);
#pragma unroll
      for(int mi = 0; mi < 4; ++mi){
        int row = mi * 16 + l15;
        bf16x8 av = ld_frag(&VtB[bb][row * 64 + ((kk * 32 + g * 8) ^ ((row & 7) << 3))]);
        acc[mi] = __builtin_amdgcn_mfma_f32_16x16x32_bf16(av, pb, acc[mi], 0, 0, 0);
      }
    }
    __builtin_amdgcn_s_setprio(0);

    if(kt + 1 < nt) WRITE_T(bb ^ 1);
    __syncthreads();
  }

  ll += __shfl_xor(ll, 16);
  ll += __shfl_xor(ll, 32);
  float inv = 1.0f / ll;

  {
    int qrow = w * 16 + l15;
#pragma unroll
    for(int mi = 0; mi < 4; ++mi){
      us4 o;
#pragma unroll
      for(int r = 0; r < 4; ++r) o[r] = f2bf(acc[mi][r] * inv);
      *(us4*)&KsB[0][qrow * 64 + ((mi * 16 + g * 4) ^ ((qrow & 7) << 3))] = o;
    }
  }
  __syncthreads();
  {
    int qrow = tid >> 2, part = tid & 3;
    us8 v0 = *(const us8*)&KsB[0][qrow * 64 + ((part * 16)     ^ ((qrow & 7) << 3))];
    us8 v1 = *(const us8*)&KsB[0][qrow * 64 + ((part * 16 + 8) ^ ((qrow & 7) << 3))];
    size_t orow = ((size_t)b * 2048 + qt * 64 + qrow) * 1024 + h * 64 + part * 16;
    *(us8*)&ctx[orow] = v0;
    *(us8*)&ctx[orow + 8] = v1;
  }
#undef LOAD_T
#undef WRITE_T
}

// ---------------- launch ----------------
extern "C" void kernel_launch(void* const* d_in, const int* in_sizes, int n_in,
                              void* d_out, int out_size, void* d_ws, size_t ws_size,
                              hipStream_t stream) {
  const float* Qf = (const float*)d_in[0];
  const float* Kf = (const float*)d_in[1];
  const float* Vf = (const float*)d_in[2];
  const int*   Mk = (const int*)d_in[3];
  const float* Wq = (const float*)d_in[4];
  const float* bq = (const float*)d_in[5];
  const float* Wk = (const float*)d_in[6];
  const float* bk = (const float*)d_in[7];
  const float* Wv = (const float*)d_in[8];
  const float* bv = (const float*)d_in[9];
  const float* Wo = (const float*)d_in[10];
  const float* bo = (const float*)d_in[11];

  const size_t MB = 1u << 20;
  char* ws = (char*)d_ws;
  unsigned short* Wqb = (unsigned short*)(ws + 0 * MB);
  unsigned short* Wkb = (unsigned short*)(ws + 2 * MB);
  unsigned short* Wvb = (unsigned short*)(ws + 4 * MB);
  unsigned short* Wob = (unsigned short*)(ws + 6 * MB);
  unsigned short* qs  = (unsigned short*)(ws + 8 * MB);
  unsigned short* ksc = (unsigned short*)(ws + 24 * MB);
  unsigned short* vTc = (unsigned short*)(ws + 40 * MB);
  unsigned short* ctx = (unsigned short*)(ws + 56 * MB);
  int* idx = (int*)(ws + 72 * MB);
  int* nk  = (int*)(ws + 73 * MB);

  mask_scan<<<4, 256, 0, stream>>>(Mk, idx, nk);
  cvt_bf16x4<<<dim3(512, 4), 256, 0, stream>>>(Wq, Wk, Wv, Wo, Wqb, Wkb, Wvb, Wob);

  const float QSCALE = 0.125f * 1.4426950408889634f;  // 1/sqrt(d_head) * log2(e)
  dim3 blk(256);
  // fused Q/K/V, XCD-co-located: grid (64, 24)
  qkv_proj<<<dim3(64, 24), blk, 0, stream>>>(Qf, Kf, Vf, Wqb, Wkb, Wvb,
                                             bq, bk, bv, qs, ksc, vTc, QSCALE,
                                             idx, nk);
  // attention over compacted keys, bh-major grid
  attn_kernel<<<dim3(64, 32), blk, 0, stream>>>(qs, ksc, vTc, nk, ctx);
  // output projection -> f32 (SWAPG grid)
  gemm_out<<<dim3(64, 8), blk, 0, stream>>>(ctx, Wob, bo, (float*)d_out, 1024);
}

// Round 14
// 173.063 us; speedup vs baseline: 1.2204x; 1.0114x over previous
//
#include <hip/hip_runtime.h>

// MHA: BS=4 SEQ=2048 D_MODEL=1024 H=16 DH=64
// R14 = R13 + f32 removed from all GEMM loops: one streaming cvt_all pass
// converts weights + Q (full) + K/V (gathered-compacted via idx) to bf16;
// qkv_proj is now 3 uniform all-bf16 GEMMs with gll16 staging both operands
// (no reg-stage cvt chain, no gather in the GEMM). attn & gemm_out = R13.

typedef __attribute__((ext_vector_type(8))) unsigned short us8;
typedef __attribute__((ext_vector_type(4))) unsigned short us4;
typedef __attribute__((ext_vector_type(4))) int i4;
typedef __attribute__((ext_vector_type(4))) float f4;
typedef __attribute__((ext_vector_type(4))) float f32x4;
typedef __attribute__((ext_vector_type(8))) __bf16 bf16x8;
typedef __attribute__((ext_vector_type(2))) unsigned u32x2;
typedef __attribute__((ext_vector_type(4))) unsigned u32x4;

#define DEV static __device__ __forceinline__

DEV unsigned short f2bf(float f){
  unsigned u = __builtin_bit_cast(unsigned, f);
  u = (u + 0x7fffu + ((u >> 16) & 1u)) >> 16;
  return (unsigned short)u;
}

DEV bf16x8 ld_frag(const unsigned short* p){
  return __builtin_bit_cast(bf16x8, *(const us8*)p);
}

// async global->LDS, 16B per lane. LDS dest wave-uniform base + lane*16; global src per-lane.
DEV void gll16(const unsigned short* gsrc, unsigned short* ldst){
  __builtin_amdgcn_global_load_lds(
      (const __attribute__((address_space(1))) unsigned int*)gsrc,
      (__attribute__((address_space(3))) unsigned int*)ldst, 16, 0, 0);
}

// load 8 f32, convert to 8 bf16 via packed cvt (RNE)
DEV us8 ld_cvt_f32x8(const float* p){
  f4 v0 = *(const f4*)p;
  f4 v1 = *(const f4*)(p + 4);
  unsigned d0, d1, d2, d3;
  asm("v_cvt_pk_bf16_f32 %0, %1, %2" : "=v"(d0) : "v"(v0[0]), "v"(v0[1]));
  asm("v_cvt_pk_bf16_f32 %0, %1, %2" : "=v"(d1) : "v"(v0[2]), "v"(v0[3]));
  asm("v_cvt_pk_bf16_f32 %0, %1, %2" : "=v"(d2) : "v"(v1[0]), "v"(v1[1]));
  asm("v_cvt_pk_bf16_f32 %0, %1, %2" : "=v"(d3) : "v"(v1[2]), "v"(v1[3]));
  u32x4 u = {d0, d1, d2, d3};
  return __builtin_bit_cast(us8, u);
}

// ---------------- mask scan: compacted unmasked-key index list ----------------
__global__ __launch_bounds__(256) void mask_scan(
    const int* __restrict__ mask, int* __restrict__ idx, int* __restrict__ nk)
{
  const int b = blockIdx.x, t = threadIdx.x;
  __shared__ int sc[256];
  int m[8]; int c = 0;
#pragma unroll
  for(int r = 0; r < 8; ++r){ m[r] = mask[b * 2048 + t * 8 + r]; c += (m[r] != 0); }
  sc[t] = c;
  __syncthreads();
  for(int s = 1; s < 256; s <<= 1){
    int v = (t >= s) ? sc[t - s] : 0;
    __syncthreads();
    sc[t] += v;
    __syncthreads();
  }
  int pos = sc[t] - c;            // exclusive prefix
  int total = sc[255];
#pragma unroll
  for(int r = 0; r < 8; ++r) if(m[r]) idx[b * 2048 + pos++] = t * 8 + r;
  int pend = (total + 127) & ~127;
  for(int p = total + t; p < pend; p += 256) idx[b * 2048 + p] = 0;
  if(t == 0) nk[b] = total;
}

// ---------------- one streaming conversion pass ----------------
// y=0..3: weights (1M elems each). y=4: Q full (8M). y=5: K gathered-compacted.
// y=6: V gathered-compacted. Each block = 2048 elems (= 2 rows of 1024).
__global__ __launch_bounds__(256) void cvt_all(
    const float* __restrict__ Wq, const float* __restrict__ Wk,
    const float* __restrict__ Wv, const float* __restrict__ Wo,
    const float* __restrict__ Qf, const float* __restrict__ Kf, const float* __restrict__ Vf,
    unsigned short* __restrict__ Wqb, unsigned short* __restrict__ Wkb,
    unsigned short* __restrict__ Wvb, unsigned short* __restrict__ Wob,
    unsigned short* __restrict__ Qb, unsigned short* __restrict__ Kbc,
    unsigned short* __restrict__ Vbc,
    const int* __restrict__ gidx, const int* __restrict__ nkarr)
{
  const int y = blockIdx.y, x = blockIdx.x, t = threadIdx.x;
  if(y < 4){
    if(x >= 512) return;
    const float* src = (y == 0) ? Wq : (y == 1) ? Wk : (y == 2) ? Wv : Wo;
    unsigned short* dst = (y == 0) ? Wqb : (y == 1) ? Wkb : (y == 2) ? Wvb : Wob;
    size_t i = (size_t)x * 2048 + t * 8;
    *(us8*)(dst + i) = ld_cvt_f32x8(src + i);
  } else if(y == 4){
    size_t i = (size_t)x * 2048 + t * 8;
    *(us8*)(Qb + i) = ld_cvt_f32x8(Qf + i);
  } else {
    const float* src = (y == 5) ? Kf : Vf;
    unsigned short* dst = (y == 5) ? Kbc : Vbc;
    int r0 = x * 2;                         // compacted flat row base (0..8191)
    int b = r0 >> 11, j = r0 & 2047;
    if(j >= ((nkarr[b] + 127) & ~127)) return;
    int rr = t >> 7;                        // 0/1: which of the 2 rows
    int srow = gidx[b * 2048 + j + rr];
    int col = (t & 127) * 8;
    *(us8*)(dst + (size_t)(r0 + rr) * 1024 + col) =
        ld_cvt_f32x8(src + ((size_t)b * 2048 + srow) * 1024 + col);
  }
}

// ---------------- Fused Q/K/V projection, all-bf16, XCD-co-located ----------------
// grid (64, 24): x = activation tile, y = z*8+ny. All operands bf16 via gll16.
// z=0: qs = (Qb@Wq^T + bq)*qscale.  z=1: ksc = Kbc@Wk^T + bk (compacted rows).
// z=2: vTc = Wv@Vbc^T + bv (transposed out, compacted cols).
__global__ __launch_bounds__(256) void qkv_proj(
    const unsigned short* __restrict__ Qb, const unsigned short* __restrict__ Kbc,
    const unsigned short* __restrict__ Vbc,
    const unsigned short* __restrict__ Wqb, const unsigned short* __restrict__ Wkb,
    const unsigned short* __restrict__ Wvb,
    const float* __restrict__ bq, const float* __restrict__ bk, const float* __restrict__ bv,
    unsigned short* __restrict__ qs, unsigned short* __restrict__ ksc,
    unsigned short* __restrict__ vTc, float qscale, const int* __restrict__ nkarr)
{
  __shared__ __align__(16) unsigned short As[128 * 64];
  __shared__ __align__(16) unsigned short Bs[128 * 64];
  const int tid = threadIdx.x;
  const int x = blockIdx.x, z = blockIdx.y >> 3, ny = blockIdx.y & 7;
  const int w = tid >> 6, l = tid & 63, g = l >> 4, l15 = l & 15;
  const int wm = w >> 1, wn = w & 1;
  const int xsw = ((l & 7) ^ (l >> 3)) << 3;

  if(z >= 1){
    const int gb = (x * 128) >> 11, j0 = (x * 128) & 2047;
    if(j0 >= ((nkarr[gb] + 127) & ~127)) return;    // uniform exit, pre-barrier
  }

  const unsigned short* Ab = (z == 0) ? Qb : (z == 1) ? Kbc : Wvb;
  const unsigned short* Bb = (z == 0) ? Wqb : (z == 1) ? Wkb : Vbc;
  const int abase = (z == 2) ? ny * 128 : x * 128;
  const int bbase = (z == 2) ? x * 128 : ny * 128;
  const int lrow = (w << 5) + (l >> 3);             // + j*8: staged row per lane

  f32x4 acc[4][4];
#pragma unroll
  for(int a = 0; a < 4; ++a)
#pragma unroll
    for(int b = 0; b < 4; ++b) acc[a][b] = (f32x4){0.f,0.f,0.f,0.f};

  for(int kt = 0; kt < 16; ++kt){
    __syncthreads();
#pragma unroll
    for(int j = 0; j < 4; ++j)
      gll16(Ab + (size_t)(abase + lrow + (j << 3)) * 1024 + kt * 64 + xsw,
            &As[((w << 5) + (j << 3)) << 6]);
#pragma unroll
    for(int j = 0; j < 4; ++j)
      gll16(Bb + (size_t)(bbase + lrow + (j << 3)) * 1024 + kt * 64 + xsw,
            &Bs[((w << 5) + (j << 3)) << 6]);
    asm volatile("s_waitcnt vmcnt(0)" ::: "memory");
    __syncthreads();
#pragma unroll
    for(int kk = 0; kk < 2; ++kk){
      bf16x8 af[4], bg[4];
#pragma unroll
      for(int mi = 0; mi < 4; ++mi){
        int row = wm * 64 + mi * 16 + l15;
        af[mi] = ld_frag(&As[row * 64 + ((kk * 32 + g * 8) ^ ((row & 7) << 3))]);
      }
#pragma unroll
      for(int ni = 0; ni < 4; ++ni){
        int row = wn * 64 + ni * 16 + l15;
        bg[ni] = ld_frag(&Bs[row * 64 + ((kk * 32 + g * 8) ^ ((row & 7) << 3))]);
      }
#pragma unroll
      for(int mi = 0; mi < 4; ++mi)
#pragma unroll
        for(int ni = 0; ni < 4; ++ni)
          acc[mi][ni] = __builtin_amdgcn_mfma_f32_16x16x32_bf16(af[mi], bg[ni], acc[mi][ni], 0, 0, 0);
    }
  }

  if(z < 2){
    const float scale = (z == 0) ? qscale : 1.0f;
    const float* bias = (z == 0) ? bq : bk;
    unsigned short* out = (z == 0) ? qs : ksc;
#pragma unroll
    for(int mi = 0; mi < 4; ++mi)
#pragma unroll
      for(int ni = 0; ni < 4; ++ni){
        int gmb = x * 128 + wm * 64 + mi * 16 + g * 4;
        int gn  = ny * 128 + wn * 64 + ni * 16 + l15;
#pragma unroll
        for(int r = 0; r < 4; ++r){
          int gm = gmb + r;
          float v = (acc[mi][ni][r] + bias[gn]) * scale;
          int b = gm >> 11, s = gm & 2047, h = gn >> 6, dh = gn & 63;
          out[(size_t)(((b << 4) + h) * 2048 + s) * 64 + dh] = f2bf(v);
        }
      }
  } else {
#pragma unroll
    for(int mi = 0; mi < 4; ++mi)
#pragma unroll
      for(int ni = 0; ni < 4; ++ni){
        int gmb = ny * 128 + wm * 64 + mi * 16 + g * 4;   // d index
        int gn  = x * 128 + wn * 64 + ni * 16 + l15;      // compacted s index
#pragma unroll
        for(int r = 0; r < 4; ++r){
          int gm = gmb + r;
          float v = acc[mi][ni][r] + bv[gm];
          int h = gm >> 6, dh = gm & 63, b = gn >> 11, s = gn & 2047;
          vTc[(size_t)(((b << 4) + h) * 64 + dh) * 2048 + s] = f2bf(v);
        }
      }
  }
}

// ---------------- out-proj GEMM (SWAPG, bf16 operands) ----------------
__global__ __launch_bounds__(256) void gemm_out(
    const unsigned short* __restrict__ Ap, const unsigned short* __restrict__ Bp,
    const float* __restrict__ bias, float* __restrict__ outp, int K)
{
  __shared__ __align__(16) unsigned short As[128 * 64];
  __shared__ __align__(16) unsigned short Bs[128 * 64];
  const int tid = threadIdx.x;
  const int gy = blockIdx.x, gx = blockIdx.y;      // SWAPG: M-tile = x
  const int w = tid >> 6, l = tid & 63, g = l >> 4, l15 = l & 15;
  const int wm = w >> 1, wn = w & 1;
  const int xsw = ((l & 7) ^ (l >> 3)) << 3;

  f32x4 acc[4][4];
#pragma unroll
  for(int a = 0; a < 4; ++a)
#pragma unroll
    for(int b = 0; b < 4; ++b) acc[a][b] = (f32x4){0.f,0.f,0.f,0.f};

  const int nkt = K >> 6;
  for(int kt = 0; kt < nkt; ++kt){
    __syncthreads();
#pragma unroll
    for(int j = 0; j < 4; ++j)
      gll16(Ap + (size_t)(gy * 128 + (w << 5) + (j << 3) + (l >> 3)) * K + kt * 64 + xsw,
            &As[((w << 5) + (j << 3)) << 6]);
#pragma unroll
    for(int j = 0; j < 4; ++j)
      gll16(Bp + (size_t)(gx * 128 + (w << 5) + (j << 3) + (l >> 3)) * K + kt * 64 + xsw,
            &Bs[((w << 5) + (j << 3)) << 6]);
    asm volatile("s_waitcnt vmcnt(0)" ::: "memory");
    __syncthreads();
#pragma unroll
    for(int kk = 0; kk < 2; ++kk){
      bf16x8 af[4], bg[4];
#pragma unroll
      for(int mi = 0; mi < 4; ++mi){
        int row = wm * 64 + mi * 16 + l15;
        af[mi] = ld_frag(&As[row * 64 + ((kk * 32 + g * 8) ^ ((row & 7) << 3))]);
      }
#pragma unroll
      for(int ni = 0; ni < 4; ++ni){
        int row = wn * 64 + ni * 16 + l15;
        bg[ni] = ld_frag(&Bs[row * 64 + ((kk * 32 + g * 8) ^ ((row & 7) << 3))]);
      }
#pragma unroll
      for(int mi = 0; mi < 4; ++mi)
#pragma unroll
        for(int ni = 0; ni < 4; ++ni)
          acc[mi][ni] = __builtin_amdgcn_mfma_f32_16x16x32_bf16(af[mi], bg[ni], acc[mi][ni], 0, 0, 0);
    }
  }

#pragma unroll
  for(int mi = 0; mi < 4; ++mi)
#pragma unroll
    for(int ni = 0; ni < 4; ++ni){
      int gmb = gy * 128 + wm * 64 + mi * 16 + g * 4;
      int gn  = gx * 128 + wn * 64 + ni * 16 + l15;
#pragma unroll
      for(int r = 0; r < 4; ++r)
        outp[(size_t)(gmb + r) * 1024 + gn] = acc[mi][ni][r] + bias[gn];
    }
}

// ---------------- Flash attention, bh-major grid (R13-proven) ----------------
__global__ __launch_bounds__(256) void attn_kernel(
    const unsigned short* __restrict__ q, const unsigned short* __restrict__ ksc,
    const unsigned short* __restrict__ vTc, const int* __restrict__ nk,
    unsigned short* __restrict__ ctx)
{
  __shared__ __align__(16) unsigned short KsB[2][64 * 64];
  __shared__ __align__(16) unsigned short VtB[2][64 * 64];
  __shared__ __align__(16) unsigned short Ps[4][16 * 64];

  const int bh = blockIdx.x;            // bh fastest -> XCD co-location
  const int qt = blockIdx.y;
  const int b  = bh >> 4, h = bh & 15;
  const int tid = threadIdx.x;
  const int w = tid >> 6, l = tid & 63, g = l >> 4, l15 = l & 15;
  const int rl = l >> 3, c8 = l & 7;

  const int nkb = nk[b];
  const int nt = (nkb + 63) >> 6;

  const unsigned short* qbase = q + ((size_t)(bh * 2048 + qt * 64 + w * 16 + l15)) * 64;
  bf16x8 bq[2];
  bq[0] = ld_frag(qbase + g * 8);
  bq[1] = ld_frag(qbase + 32 + g * 8);

  const unsigned short* kbase = ksc + (size_t)bh * 2048 * 64;
  const unsigned short* vbase = vTc + (size_t)bh * 64 * 2048;

  const unsigned short* kg0 = kbase + (size_t)(w * 16 + rl) * 64 + c8 * 8;
  const unsigned short* vg0 = vbase + (size_t)(w * 16 + rl) * 2048 + c8 * 8;
  const int lo0 = (w * 16 + rl) * 64 + ((c8 ^ rl) << 3);
  const int lo1 = lo0 + 8 * 64;

  us8 kr0, kr1, vr0, vr1;
#define LOAD_T(kt_) do{                                        \
    kr0 = *(const us8*)(kg0 + (size_t)(kt_) * 4096);           \
    kr1 = *(const us8*)(kg0 + (size_t)(kt_) * 4096 + 512);     \
    vr0 = *(const us8*)(vg0 + (size_t)(kt_) * 64);             \
    vr1 = *(const us8*)(vg0 + (size_t)(kt_) * 64 + 8 * 2048);  \
  }while(0)
#define WRITE_T(bb_) do{                                       \
    *(us8*)&KsB[bb_][lo0] = kr0;                               \
    *(us8*)&KsB[bb_][lo1] = kr1;                               \
    *(us8*)&VtB[bb_][lo0] = vr0;                               \
    *(us8*)&VtB[bb_][lo1] = vr1;                               \
  }while(0)

  f32x4 acc[4];
#pragma unroll
  for(int mi = 0; mi < 4; ++mi) acc[mi] = (f32x4){0.f,0.f,0.f,0.f};
  float ll = 0.f;

  LOAD_T(0);
  WRITE_T(0);
  __syncthreads();

  for(int kt = 0; kt < nt; ++kt){
    const int bb = kt & 1;
    if(kt + 1 < nt) LOAD_T(kt + 1);

    f32x4 sa[4];
#pragma unroll
    for(int mi = 0; mi < 4; ++mi) sa[mi] = (f32x4){0.f,0.f,0.f,0.f};
    __builtin_amdgcn_s_setprio(1);
#pragma unroll
    for(int kk = 0; kk < 2; ++kk){
#pragma unroll
      for(int mi = 0; mi < 4; ++mi){
        int row = mi * 16 + l15;
        bf16x8 af = ld_frag(&KsB[bb][row * 64 + ((kk * 32 + g * 8) ^ ((row & 7) << 3))]);
        sa[mi] = __builtin_amdgcn_mfma_f32_16x16x32_bf16(af, bq[kk], sa[mi], 0, 0, 0);
      }
    }
    __builtin_amdgcn_s_setprio(0);

    float p[4][4];
    if((kt + 1) * 64 <= nkb){
#pragma unroll
      for(int mi = 0; mi < 4; ++mi)
#pragma unroll
        for(int r = 0; r < 4; ++r){
          p[mi][r] = __builtin_amdgcn_exp2f(sa[mi][r]);
          ll += p[mi][r];
        }
    } else {
      int kb0 = kt * 64 + g * 4;
#pragma unroll
      for(int mi = 0; mi < 4; ++mi)
#pragma unroll
        for(int r = 0; r < 4; ++r){
          float e = __builtin_amdgcn_exp2f(sa[mi][r]);
          p[mi][r] = (kb0 + mi * 16 + r < nkb) ? e : 0.f;
          ll += p[mi][r];
        }
    }

#pragma unroll
    for(int mi = 0; mi < 4; ++mi){
      unsigned d0, d1;
      asm("v_cvt_pk_bf16_f32 %0, %1, %2" : "=v"(d0) : "v"(p[mi][0]), "v"(p[mi][1]));
      asm("v_cvt_pk_bf16_f32 %0, %1, %2" : "=v"(d1) : "v"(p[mi][2]), "v"(p[mi][3]));
      u32x2 dd = {d0, d1};
      *(u32x2*)&Ps[w][l15 * 64 + ((mi * 16 + g * 4) ^ ((l15 & 7) << 3))] = dd;
    }

    __builtin_amdgcn_s_setprio(1);
#pragma unroll
    for(int kk = 0; kk < 2; ++kk){
      bf16x8 pb = ld_frag(&Ps[w][l15 * 64 + ((kk * 32 + g * 8) ^ ((l15 & 7) << 3))]);
#pragma unroll
      for(int mi = 0; mi < 4; ++mi){
        int row = mi * 16 + l15;
        bf16x8 av = ld_frag(&VtB[bb][row * 64 + ((kk * 32 + g * 8) ^ ((row & 7) << 3))]);
        acc[mi] = __builtin_amdgcn_mfma_f32_16x16x32_bf16(av, pb, acc[mi], 0, 0, 0);
      }
    }
    __builtin_amdgcn_s_setprio(0);

    if(kt + 1 < nt) WRITE_T(bb ^ 1);
    __syncthreads();
  }

  ll += __shfl_xor(ll, 16);
  ll += __shfl_xor(ll, 32);
  float inv = 1.0f / ll;

  {
    int qrow = w * 16 + l15;
#pragma unroll
    for(int mi = 0; mi < 4; ++mi){
      us4 o;
#pragma unroll
      for(int r = 0; r < 4; ++r) o[r] = f2bf(acc[mi][r] * inv);
      *(us4*)&KsB[0][qrow * 64 + ((mi * 16 + g * 4) ^ ((qrow & 7) << 3))] = o;
    }
  }
  __syncthreads();
  {
    int qrow = tid >> 2, part = tid & 3;
    us8 v0 = *(const us8*)&KsB[0][qrow * 64 + ((part * 16)     ^ ((qrow & 7) << 3))];
    us8 v1 = *(const us8*)&KsB[0][qrow * 64 + ((part * 16 + 8) ^ ((qrow & 7) << 3))];
    size_t orow = ((size_t)b * 2048 + qt * 64 + qrow) * 1024 + h * 64 + part * 16;
    *(us8*)&ctx[orow] = v0;
    *(us8*)&ctx[orow + 8] = v1;
  }
#undef LOAD_T
#undef WRITE_T
}

// ---------------- launch ----------------
extern "C" void kernel_launch(void* const* d_in, const int* in_sizes, int n_in,
                              void* d_out, int out_size, void* d_ws, size_t ws_size,
                              hipStream_t stream) {
  const float* Qf = (const float*)d_in[0];
  const float* Kf = (const float*)d_in[1];
  const float* Vf = (const float*)d_in[2];
  const int*   Mk = (const int*)d_in[3];
  const float* Wq = (const float*)d_in[4];
  const float* bq = (const float*)d_in[5];
  const float* Wk = (const float*)d_in[6];
  const float* bk = (const float*)d_in[7];
  const float* Wv = (const float*)d_in[8];
  const float* bv = (const float*)d_in[9];
  const float* Wo = (const float*)d_in[10];
  const float* bo = (const float*)d_in[11];

  const size_t MB = 1u << 20;
  char* ws = (char*)d_ws;
  unsigned short* Wqb = (unsigned short*)(ws + 0 * MB);
  unsigned short* Wkb = (unsigned short*)(ws + 2 * MB);
  unsigned short* Wvb = (unsigned short*)(ws + 4 * MB);
  unsigned short* Wob = (unsigned short*)(ws + 6 * MB);
  unsigned short* qs  = (unsigned short*)(ws + 8 * MB);
  unsigned short* ksc = (unsigned short*)(ws + 24 * MB);
  unsigned short* vTc = (unsigned short*)(ws + 40 * MB);
  unsigned short* ctx = (unsigned short*)(ws + 56 * MB);
  int* idx = (int*)(ws + 72 * MB);
  int* nk  = (int*)(ws + 73 * MB);
  unsigned short* Qb  = (unsigned short*)(ws + 74 * MB);
  unsigned short* Kbc = (unsigned short*)(ws + 90 * MB);
  unsigned short* Vbc = (unsigned short*)(ws + 106 * MB);

  mask_scan<<<4, 256, 0, stream>>>(Mk, idx, nk);
  // one streaming conversion pass (weights + Q full + K/V gathered-compacted)
  cvt_all<<<dim3(4096, 7), 256, 0, stream>>>(Wq, Wk, Wv, Wo, Qf, Kf, Vf,
                                             Wqb, Wkb, Wvb, Wob, Qb, Kbc, Vbc,
                                             idx, nk);

  const float QSCALE = 0.125f * 1.4426950408889634f;  // 1/sqrt(d_head) * log2(e)
  dim3 blk(256);
  // fused Q/K/V, all-bf16, XCD-co-located: grid (64, 24)
  qkv_proj<<<dim3(64, 24), blk, 0, stream>>>(Qb, Kbc, Vbc, Wqb, Wkb, Wvb,
                                             bq, bk, bv, qs, ksc, vTc, QSCALE, nk);
  // attention over compacted keys, bh-major grid
  attn_kernel<<<dim3(64, 32), blk, 0, stream>>>(qs, ksc, vTc, nk, ctx);
  // output projection -> f32 (SWAPG grid)
  gemm_out<<<dim3(64, 8), blk, 0, stream>>>(ctx, Wob, bo, (float*)d_out, 1024);
}